// Round 2
// baseline (1629.632 us; speedup 1.0000x reference)
//
#include <hip/hip_runtime.h>
#include <hip/hip_bf16.h>

typedef __hip_bfloat16 bf16;

#define F 18
#define P 128
#define H 256
#define HEADS 8
#define HD 32
#define NCLS 625
#define FPH (F*P*H)

// workspace layout (float slots from base)
#define OF_FLAG   0
#define OF_PTN    16
#define OF_RT     48
#define OF_W      80
#define OF_OSUM   128
#define OF_CTX    512
#define OF_G      (OF_CTX + FPH)
#define OF_INP    (OF_G + FPH)
#define OF_WTS    (OF_INP + FPH)
// weight sub-offsets (relative to OF_WTS)
#define WO_HALTW  0
#define WO_HALTB  256
#define WO_CLSB   272
#define WO_CLSW   912
#define WO_WQ     160912
#define WO_WK     357520
#define WO_WV     554128
#define WO_WO     750736
#define WO_BQ     947344
#define WO_BK     948112
#define WO_BV     948880
#define WO_BO     949648
#define WTS_TOTAL 950416
#define QKV_ELEMS 2555904   // 9984*256 bf16 elements per buffer

__device__ __forceinline__ float b2f(bf16 x){ return __bfloat162float(x); }
__device__ __forceinline__ unsigned short f2bu(float x){
    union { __hip_bfloat16 h; unsigned short u; } cv; cv.h = __float2bfloat16(x); return cv.u;
}
__device__ __forceinline__ float bu2f(unsigned short u){
    union { unsigned int x; float f; } cv; cv.x = ((unsigned int)u) << 16; return cv.f;
}
__device__ __forceinline__ void b2x2(unsigned int u, float& a, float& b){
    union { unsigned int x; float f; } c1, c2;
    c1.x = u << 16; c2.x = u & 0xffff0000u; a = c1.f; b = c2.f;
}
__device__ __forceinline__ int imin(int a,int b){ return a<b?a:b; }
__device__ __forceinline__ int imax(int a,int b){ return a>b?a:b; }

// ---------------------------------------------------------------------------
// dtype probe: low 16 bits of each word. bf16 data -> a real bf16 ~N(0,1)
// (exponent in [120,130] ~99%). fp32 data -> random mantissa bits (~4%).
// ---------------------------------------------------------------------------
__global__ __launch_bounds__(256) void k_detect(const unsigned int* __restrict__ embw,
                                                float* __restrict__ ws)
{
    __shared__ int cnt;
    if (threadIdx.x == 0) cnt = 0;
    __syncthreads();
    int c = 0;
    for (int i = threadIdx.x; i < 512; i += 256){
        unsigned int e = (embw[i] >> 7) & 0xffu;
        if (e >= 120u && e <= 130u) c++;
    }
    atomicAdd(&cnt, c);
    __syncthreads();
    if (threadIdx.x == 0) ws[OF_FLAG] = (cnt > 256) ? 1.f : 0.f;
}

// ---------------------------------------------------------------------------
// convert all weights (+embed) into fp32 workspace copies per detected dtype
// ---------------------------------------------------------------------------
struct ConvArgs {
    const void* src[13];
    int off[13];
    int n[13];
};
__global__ __launch_bounds__(256) void k_convert(ConvArgs a, float* __restrict__ ws)
{
    int gid = blockIdx.x*256 + threadIdx.x;
    const int isbf = (ws[OF_FLAG] != 0.f);
#pragma unroll
    for (int t = 0; t < 13; ++t){
        if (gid < a.n[t]){
            float v = isbf ? b2f(((const bf16*)a.src[t])[gid])
                           : ((const float*)a.src[t])[gid];
            ws[a.off[t] + gid] = v;
            return;
        }
        gid -= a.n[t];
    }
}

// ---------------------------------------------------------------------------
// halting probability + ACT state update (one block per frame)
// ---------------------------------------------------------------------------
__global__ __launch_bounds__(128) void k_halt(const float* __restrict__ inputs,
        const float* __restrict__ hW, const float* __restrict__ hB,
        float* __restrict__ ws)
{
    __shared__ float hw[H];
    __shared__ float red[128];
    const int f = blockIdx.x, t = threadIdx.x;
    for (int i = t; i < H; i += 128) hw[i] = hW[i];
    __syncthreads();
    const float* row = inputs + (size_t)(f*P + t)*H;
    float acc = hB[0];
    for (int i = 0; i < H; i++) acc = fmaf(row[i], hw[i], acc);
    red[t] = 1.f/(1.f + __expf(-acc));
    __syncthreads();
    for (int s = 64; s > 0; s >>= 1){ if (t < s) red[t] += red[t+s]; __syncthreads(); }
    if (t == 0){
        float pf = red[0] * (1.f/P);
        float pt = ws[OF_PTN + f], rt = ws[OF_RT + f];
        float run  = (pt < 1.f) ? 1.f : 0.f;
        float cond = (pt + pf*run > 0.99f) ? 1.f : 0.f;
        float nh   = cond*run;
        run = (1.f - cond)*run;
        pt += pf*run;
        rt += nh*(1.f - pt);
        pt += nh*rt;
        ws[OF_PTN + f] = pt; ws[OF_RT + f] = rt;
        ws[OF_W   + f] = pf*run + nh*rt;
    }
}

// ---------------------------------------------------------------------------
// fused QKV projection with window gather. fp32 in/weights, bf16 out.
// ---------------------------------------------------------------------------
__global__ __launch_bounds__(256) void k_qkv(const float* __restrict__ X,
        const float* __restrict__ Wq, const float* __restrict__ biasq,
        const float* __restrict__ Wk, const float* __restrict__ biask,
        const float* __restrict__ Wv, const float* __restrict__ biasv,
        bf16* __restrict__ qo, bf16* __restrict__ ko, bf16* __restrict__ vo,
        int SP, int S)
{
    __shared__ __align__(16) float As [16][68];
    __shared__ __align__(16) float BsQ[16][68];
    __shared__ __align__(16) float BsK[16][68];
    __shared__ __align__(16) float BsV[16][68];
    const int tid = threadIdx.x;
    const int m0 = blockIdx.x*64, n0 = blockIdx.y*64;
    const int tx = tid & 15, ty = tid >> 4;
    const int am = tid >> 2, akk = (tid & 3) << 2;
    const int gm = m0 + am;
    const int w  = gm / S;
    const float* arow = X + (size_t)(gm - w*SP) * H;
    const int bkk = tid >> 4, bn = (tid & 15) << 2;

    float acc[3][4][4];
#pragma unroll
    for (int m=0;m<3;m++)
#pragma unroll
      for (int i=0;i<4;i++)
#pragma unroll
        for (int j=0;j<4;j++) acc[m][i][j] = 0.f;

    for (int k0 = 0; k0 < H; k0 += 16){
        float4 av = *(const float4*)(arow + k0 + akk);
        const size_t wofs = (size_t)(k0 + bkk)*H + n0 + bn;
        float4 fq = *(const float4*)(Wq + wofs);
        float4 fk = *(const float4*)(Wk + wofs);
        float4 fv = *(const float4*)(Wv + wofs);
        As[akk+0][am]=av.x; As[akk+1][am]=av.y; As[akk+2][am]=av.z; As[akk+3][am]=av.w;
        *(float4*)&BsQ[bkk][bn] = fq;
        *(float4*)&BsK[bkk][bn] = fk;
        *(float4*)&BsV[bkk][bn] = fv;
        __syncthreads();
#pragma unroll
        for (int kk = 0; kk < 16; ++kk){
            const float4 a4 = *(const float4*)&As [kk][ty<<2];
            const float4 q4 = *(const float4*)&BsQ[kk][tx<<2];
            const float4 k4 = *(const float4*)&BsK[kk][tx<<2];
            const float4 v4 = *(const float4*)&BsV[kk][tx<<2];
            const float aa[4]={a4.x,a4.y,a4.z,a4.w};
            const float qq[4]={q4.x,q4.y,q4.z,q4.w};
            const float kv[4]={k4.x,k4.y,k4.z,k4.w};
            const float vv[4]={v4.x,v4.y,v4.z,v4.w};
#pragma unroll
            for (int i=0;i<4;i++)
#pragma unroll
              for (int j=0;j<4;j++){
                acc[0][i][j] = fmaf(aa[i], qq[j], acc[0][i][j]);
                acc[1][i][j] = fmaf(aa[i], kv[j], acc[1][i][j]);
                acc[2][i][j] = fmaf(aa[i], vv[j], acc[2][i][j]);
              }
        }
        __syncthreads();
    }
    const int orow = m0 + (ty<<2);
    const int ocol = n0 + (tx<<2);
    float bqv[4], bkv[4], bvv[4];
#pragma unroll
    for (int j=0;j<4;j++){ bqv[j]=biasq[ocol+j]; bkv[j]=biask[ocol+j]; bvv[j]=biasv[ocol+j]; }
#pragma unroll
    for (int i=0;i<4;i++){
        ushort4 rq, rk, rv;
        rq.x=f2bu(acc[0][i][0]+bqv[0]); rq.y=f2bu(acc[0][i][1]+bqv[1]);
        rq.z=f2bu(acc[0][i][2]+bqv[2]); rq.w=f2bu(acc[0][i][3]+bqv[3]);
        rk.x=f2bu(acc[1][i][0]+bkv[0]); rk.y=f2bu(acc[1][i][1]+bkv[1]);
        rk.z=f2bu(acc[1][i][2]+bkv[2]); rk.w=f2bu(acc[1][i][3]+bkv[3]);
        rv.x=f2bu(acc[2][i][0]+bvv[0]); rv.y=f2bu(acc[2][i][1]+bvv[1]);
        rv.z=f2bu(acc[2][i][2]+bvv[2]); rv.w=f2bu(acc[2][i][3]+bvv[3]);
        *(ushort4*)(qo + (size_t)(orow+i)*H + ocol) = rq;
        *(ushort4*)(ko + (size_t)(orow+i)*H + ocol) = rk;
        *(ushort4*)(vo + (size_t)(orow+i)*H + ocol) = rv;
    }
}

// ---------------------------------------------------------------------------
// flash attention per (window, head, 64-row q-tile). hd=32. bf16 in, bf16 out
// (in-place into qb). thread (qr, c): row qr, dim slice c*8..c*8+7.
// ---------------------------------------------------------------------------
__global__ __launch_bounds__(256) void k_attn(const bf16* __restrict__ qb,
        const bf16* __restrict__ kb, const bf16* __restrict__ vb,
        bf16* __restrict__ ob, int S, int nqt)
{
    __shared__ __align__(16) float Ks[64][36];
    __shared__ __align__(16) float Vs[64][36];
    __shared__ float Ss[64][65];
    const int bid = blockIdx.x;
    const int qt = bid % nqt;
    const int rest = bid / nqt;
    const int h = rest % HEADS;
    const int w = rest / HEADS;
    const int tid = threadIdx.x;
    const int qr = tid >> 2, c = tid & 3, d0 = c << 3;
    const size_t hofs = (size_t)h * HD;
    const int qrow = w*S + qt*64 + qr;
    const bf16* qp = qb + (size_t)qrow*H + hofs + d0;
    float qf[8];
    {
        uint4 qw = *(const uint4*)qp;
        b2x2(qw.x, qf[0], qf[1]); b2x2(qw.y, qf[2], qf[3]);
        b2x2(qw.z, qf[4], qf[5]); b2x2(qw.w, qf[6], qf[7]);
        const float sc = 0.17677669529663687f;  // 1/sqrt(32)
#pragma unroll
        for (int i=0;i<8;i++) qf[i] *= sc;
    }
    float m = -1e30f, l = 0.f;
    float o[8] = {0,0,0,0,0,0,0,0};
    const size_t tbase = (size_t)(w*S)*H + hofs;
    const int nkt = S >> 6;
    for (int kt = 0; kt < nkt; ++kt){
        const bf16* ksrc = kb + tbase + (size_t)(kt*64 + qr)*H + d0;
        const bf16* vsrc = vb + tbase + (size_t)(kt*64 + qr)*H + d0;
        uint4 kw = *(const uint4*)ksrc;
        uint4 vw = *(const uint4*)vsrc;
        float kf[8], vf[8];
        b2x2(kw.x, kf[0], kf[1]); b2x2(kw.y, kf[2], kf[3]);
        b2x2(kw.z, kf[4], kf[5]); b2x2(kw.w, kf[6], kf[7]);
        b2x2(vw.x, vf[0], vf[1]); b2x2(vw.y, vf[2], vf[3]);
        b2x2(vw.z, vf[4], vf[5]); b2x2(vw.w, vf[6], vf[7]);
        *(float4*)&Ks[qr][d0]   = *(float4*)&kf[0];
        *(float4*)&Ks[qr][d0+4] = *(float4*)&kf[4];
        *(float4*)&Vs[qr][d0]   = *(float4*)&vf[0];
        *(float4*)&Vs[qr][d0+4] = *(float4*)&vf[4];
        __syncthreads();
        float mloc = -1e30f;
#pragma unroll 8
        for (int j = 0; j < 64; ++j){
            const float4 k0 = *(const float4*)&Ks[j][d0];
            const float4 k1 = *(const float4*)&Ks[j][d0+4];
            float pd = qf[0]*k0.x + qf[1]*k0.y + qf[2]*k0.z + qf[3]*k0.w
                     + qf[4]*k1.x + qf[5]*k1.y + qf[6]*k1.z + qf[7]*k1.w;
            pd += __shfl_xor(pd, 1);
            pd += __shfl_xor(pd, 2);
            if (c == (j & 3)) Ss[qr][j] = pd;
            mloc = fmaxf(mloc, pd);
        }
        const float mnew  = fmaxf(m, mloc);
        const float alpha = __expf(m - mnew);
        l *= alpha;
#pragma unroll
        for (int i=0;i<8;i++) o[i] *= alpha;
        m = mnew;
#pragma unroll 8
        for (int j = 0; j < 64; ++j){
            const float e = __expf(Ss[qr][j] - mnew);
            l += e;
            const float4 v0 = *(const float4*)&Vs[j][d0];
            const float4 v1 = *(const float4*)&Vs[j][d0+4];
            o[0]=fmaf(e,v0.x,o[0]); o[1]=fmaf(e,v0.y,o[1]);
            o[2]=fmaf(e,v0.z,o[2]); o[3]=fmaf(e,v0.w,o[3]);
            o[4]=fmaf(e,v1.x,o[4]); o[5]=fmaf(e,v1.y,o[5]);
            o[6]=fmaf(e,v1.z,o[6]); o[7]=fmaf(e,v1.w,o[7]);
        }
        __syncthreads();
    }
    const float inv = 1.f / l;
    bf16* op = ob + (size_t)qrow*H + hofs + d0;
    unsigned int p0 = (unsigned int)f2bu(o[0]*inv) | ((unsigned int)f2bu(o[1]*inv) << 16);
    unsigned int p1 = (unsigned int)f2bu(o[2]*inv) | ((unsigned int)f2bu(o[3]*inv) << 16);
    unsigned int p2 = (unsigned int)f2bu(o[4]*inv) | ((unsigned int)f2bu(o[5]*inv) << 16);
    unsigned int p3 = (unsigned int)f2bu(o[6]*inv) | ((unsigned int)f2bu(o[7]*inv) << 16);
    uint4 st; st.x=p0; st.y=p1; st.z=p2; st.w=p3;
    *(uint4*)op = st;
}

// ---------------------------------------------------------------------------
// output projection + overlap-add accumulate: atomicAdd 0.25*(y+bo)/cnt into g
// ---------------------------------------------------------------------------
__global__ __launch_bounds__(256) void k_oproj(const bf16* __restrict__ X,
        const float* __restrict__ W, const float* __restrict__ bias,
        float* __restrict__ g, int S, int nw)
{
    __shared__ __align__(16) float As[16][68];
    __shared__ __align__(16) float Bs[16][68];
    const int tid = threadIdx.x;
    const int m0 = blockIdx.x*64, n0 = blockIdx.y*64;
    const int tx = tid & 15, ty = tid >> 4;
    const int am = tid >> 2, akk = (tid & 3) << 2;
    const bf16* arow = X + (size_t)(m0 + am) * H;
    const int bkk = tid >> 4, bn = (tid & 15) << 2;
    float acc[4][4];
#pragma unroll
    for (int i=0;i<4;i++)
#pragma unroll
      for (int j=0;j<4;j++) acc[i][j] = 0.f;

    for (int k0 = 0; k0 < H; k0 += 16){
        ushort4 aw = *(const ushort4*)(arow + k0 + akk);
        float4 fb = *(const float4*)(W + (size_t)(k0 + bkk)*H + n0 + bn);
        As[akk+0][am]=bu2f(aw.x); As[akk+1][am]=bu2f(aw.y);
        As[akk+2][am]=bu2f(aw.z); As[akk+3][am]=bu2f(aw.w);
        *(float4*)&Bs[bkk][bn] = fb;
        __syncthreads();
#pragma unroll
        for (int kk = 0; kk < 16; ++kk){
            const float4 a4 = *(const float4*)&As[kk][ty<<2];
            const float4 b4 = *(const float4*)&Bs[kk][tx<<2];
            const float aa[4]={a4.x,a4.y,a4.z,a4.w};
            const float bb[4]={b4.x,b4.y,b4.z,b4.w};
#pragma unroll
            for (int i=0;i<4;i++)
#pragma unroll
              for (int j=0;j<4;j++) acc[i][j] = fmaf(aa[i], bb[j], acc[i][j]);
        }
        __syncthreads();
    }
    const int orow = m0 + (ty<<2);
    const int ocol = n0 + (tx<<2);
    const int s = S >> 7;
    float bv[4];
#pragma unroll
    for (int j=0;j<4;j++) bv[j] = bias[ocol+j];
#pragma unroll
    for (int i=0;i<4;i++){
        const int gm = orow + i;
        const int w = gm / S;
        const int pos = gm - w*S;
        const int f = w + (pos >> 7);
        const int p = pos & 127;
        const int cnt = imin(nw-1, f) - imax(0, f - s + 1) + 1;
        const float scl = 0.25f / (float)cnt;
        float* dst = g + (size_t)(f*P + p)*H + ocol;
        atomicAdd(dst+0, (acc[i][0]+bv[0])*scl);
        atomicAdd(dst+1, (acc[i][1]+bv[1])*scl);
        atomicAdd(dst+2, (acc[i][2]+bv[2])*scl);
        atomicAdd(dst+3, (acc[i][3]+bv[3])*scl);
    }
}

// ---------------------------------------------------------------------------
// transition: inputs <- g (temporal); context <- g*w + context*(1-w)
// ---------------------------------------------------------------------------
__global__ __launch_bounds__(256) void k_transition(const float* __restrict__ g,
        const float* __restrict__ ws, float* __restrict__ inputs,
        float* __restrict__ context)
{
    const int idx = blockIdx.x*256 + threadIdx.x;
    const int f = idx >> 15;          // /(P*H)=32768
    const float tval = g[idx];
    const float wf = ws[OF_W + f];
    inputs[idx] = tval;
    context[idx] = tval*wf + context[idx]*(1.f - wf);
}

// ---------------------------------------------------------------------------
// reduce context over all rows -> osum[256]
// ---------------------------------------------------------------------------
__global__ __launch_bounds__(256) void k_reduce(const float* __restrict__ context,
        float* __restrict__ osum)
{
    const int hcol = threadIdx.x;
    const float* base = context + (size_t)blockIdx.x * 64 * H;
    float s = 0.f;
#pragma unroll 8
    for (int r = 0; r < 64; ++r) s += base[(size_t)r*H + hcol];
    atomicAdd(&osum[hcol], s);
}

// ---------------------------------------------------------------------------
// classes = osum @ cls_W + cls_b  (softmax-row-sum identity kills marginal)
// ---------------------------------------------------------------------------
__global__ __launch_bounds__(256) void k_classes(const float* __restrict__ ws,
        void* __restrict__ out)
{
    __shared__ float os[H];
    const int tid = threadIdx.x;
    os[tid] = ws[OF_OSUM + tid];
    __syncthreads();
    const int n = blockIdx.x*256 + tid;
    if (n < NCLS){
        const float* clsW = ws + OF_WTS + WO_CLSW;
        float acc = ws[OF_WTS + WO_CLSB + n];
        for (int hh = 0; hh < H; ++hh) acc = fmaf(os[hh], clsW[(size_t)hh*NCLS + n], acc);
        if (ws[OF_FLAG] != 0.f) ((bf16*)out)[n] = __float2bfloat16(acc);
        else                    ((float*)out)[n] = acc;
    }
}

// ---------------------------------------------------------------------------
extern "C" void kernel_launch(void* const* d_in, const int* in_sizes, int n_in,
                              void* d_out, int out_size, void* d_ws, size_t ws_size,
                              hipStream_t stream)
{
    (void)in_sizes; (void)n_in; (void)out_size; (void)ws_size;
    float* WS = (float*)d_ws;
    float* context = WS + OF_CTX;
    float* g       = WS + OF_G;
    float* inputs  = WS + OF_INP;
    float* wts     = WS + OF_WTS;
    bf16*  qb      = (bf16*)(wts + WTS_TOTAL);
    bf16*  kb      = qb + QKV_ELEMS;
    bf16*  vb      = kb + QKV_ELEMS;
    // total ws: (512 + 3*FPH + WTS_TOTAL)*4 + 3*QKV_ELEMS*2 ≈ 26.2 MB

    // zero flag/state/osum/context/g in one shot
    hipMemsetAsync(WS, 0, (size_t)(OF_INP)*4, stream);
    k_detect<<<1, 256, 0, stream>>>((const unsigned int*)d_in[0], WS);

    ConvArgs ca;
    const int srcs[13] = {0, 3, 4, 8, 9, 10, 12, 14, 16, 11, 13, 15, 17};
    const int offs[13] = {OF_INP,
        OF_WTS+WO_HALTW, OF_WTS+WO_HALTB, OF_WTS+WO_CLSW, OF_WTS+WO_CLSB,
        OF_WTS+WO_WQ, OF_WTS+WO_WK, OF_WTS+WO_WV, OF_WTS+WO_WO,
        OF_WTS+WO_BQ, OF_WTS+WO_BK, OF_WTS+WO_BV, OF_WTS+WO_BO};
    const int ns[13]  = {FPH, H, 1, H*NCLS, NCLS,
        3*H*H, 3*H*H, 3*H*H, 3*H*H, 3*H, 3*H, 3*H, 3*H};
    int total = 0;
    for (int t = 0; t < 13; ++t){ ca.src[t] = d_in[srcs[t]]; ca.off[t] = offs[t]; ca.n[t] = ns[t]; total += ns[t]; }
    k_convert<<<(total + 255)/256, 256, 0, stream>>>(ca, WS);

    const int scales[3] = {2, 4, 6};
    for (int it = 0; it < 2; ++it){
        k_halt<<<F, 128, 0, stream>>>(inputs, wts + WO_HALTW, wts + WO_HALTB, WS);
        hipMemsetAsync(g, 0, (size_t)FPH*4, stream);
        for (int i = 0; i < 3; ++i){
            const int s = scales[i];
            const int nw = F - s + 1;
            const int S = s*P;
            const int tokens = nw*S;
            const size_t woff = (size_t)i*H*H;
            const size_t boff = (size_t)i*H;
            k_qkv<<<dim3(tokens/64, H/64), 256, 0, stream>>>(inputs,
                wts+WO_WQ+woff, wts+WO_BQ+boff, wts+WO_WK+woff, wts+WO_BK+boff,
                wts+WO_WV+woff, wts+WO_BV+boff, qb, kb, vb, (s-1)*P, S);
            k_attn<<<nw*HEADS*(S/64), 256, 0, stream>>>(qb, kb, vb, qb, S, S/64);
            k_oproj<<<dim3(tokens/64, H/64), 256, 0, stream>>>(qb,
                wts+WO_WO+woff, wts+WO_BO+boff, g, S, nw);
        }
        k_transition<<<FPH/256, 256, 0, stream>>>(g, WS, inputs, context);
    }
    k_reduce<<<(F*P)/64, 256, 0, stream>>>(context, WS + OF_OSUM);
    k_classes<<<3, 256, 0, stream>>>(WS, d_out);
}

// Round 4
// 825.767 us; speedup vs baseline: 1.9735x; 1.9735x over previous
//
#include <hip/hip_runtime.h>
#include <hip/hip_bf16.h>

typedef __hip_bfloat16 bf16;

#define F 18
#define P 128
#define H 256
#define HEADS 8
#define HD 32
#define NCLS 625
#define FPH (F*P*H)

// workspace layout (float slots from base)
#define OF_FLAG   0
#define OF_PTN    16
#define OF_RT     48
#define OF_W      80
#define OF_OSUM   128
#define OF_CTX    512
#define OF_G      (OF_CTX + FPH)
#define OF_INP    (OF_G + FPH)
#define OF_WTS    (OF_INP + FPH)
// weight sub-offsets (relative to OF_WTS)
#define WO_HALTW  0
#define WO_HALTB  256
#define WO_CLSB   272
#define WO_CLSW   912
#define WO_WQ     160912
#define WO_WK     357520
#define WO_WV     554128
#define WO_WO     750736
#define WO_BQ     947344
#define WO_BK     948112
#define WO_BV     948880
#define WO_BO     949648
#define WTS_TOTAL 950416
#define QKV_ELEMS 2555904   // 9984*256 bf16 elements per buffer

typedef __attribute__((ext_vector_type(8))) short s8v;   // A/B frag, 16x16x32 bf16
typedef __attribute__((ext_vector_type(4))) short s4v;   // A/B frag, 16x16x16 bf16
typedef __attribute__((ext_vector_type(4))) float f4v;   // C/D frag

__device__ __forceinline__ float b2f(bf16 x){ return __bfloat162float(x); }
__device__ __forceinline__ unsigned short f2bu(float x){
    union { __hip_bfloat16 h; unsigned short u; } cv; cv.h = __float2bfloat16(x); return cv.u;
}
__device__ __forceinline__ float bu2f(unsigned short u){
    union { unsigned int x; float f; } cv; cv.x = ((unsigned int)u) << 16; return cv.f;
}
__device__ __forceinline__ unsigned int pk2(float a, float b){
    return (unsigned int)f2bu(a) | ((unsigned int)f2bu(b) << 16);
}
__device__ __forceinline__ int imin(int a,int b){ return a<b?a:b; }
__device__ __forceinline__ int imax(int a,int b){ return a>b?a:b; }

// ---------------------------------------------------------------------------
// dtype probe: low 16 bits of each word. bf16 data -> real bf16 ~N(0,1)
// (exponent in [120,130] ~99%). fp32 data -> random mantissa bits (~4%).
// ---------------------------------------------------------------------------
__global__ __launch_bounds__(256) void k_detect(const unsigned int* __restrict__ embw,
                                                float* __restrict__ ws)
{
    __shared__ int cnt;
    if (threadIdx.x == 0) cnt = 0;
    __syncthreads();
    int c = 0;
    for (int i = threadIdx.x; i < 512; i += 256){
        unsigned int e = (embw[i] >> 7) & 0xffu;
        if (e >= 120u && e <= 130u) c++;
    }
    atomicAdd(&cnt, c);
    __syncthreads();
    if (threadIdx.x == 0) ws[OF_FLAG] = (cnt > 256) ? 1.f : 0.f;
}

// ---------------------------------------------------------------------------
// convert all weights (+embed) into fp32 workspace copies per detected dtype
// ---------------------------------------------------------------------------
struct ConvArgs {
    const void* src[13];
    int off[13];
    int n[13];
};
__global__ __launch_bounds__(256) void k_convert(ConvArgs a, float* __restrict__ ws)
{
    int gid = blockIdx.x*256 + threadIdx.x;
    const int isbf = (ws[OF_FLAG] != 0.f);
#pragma unroll
    for (int t = 0; t < 13; ++t){
        if (gid < a.n[t]){
            float v = isbf ? b2f(((const bf16*)a.src[t])[gid])
                           : ((const float*)a.src[t])[gid];
            ws[a.off[t] + gid] = v;
            return;
        }
        gid -= a.n[t];
    }
}

// ---------------------------------------------------------------------------
// halting probability + ACT state update (one block per frame)
// ---------------------------------------------------------------------------
__global__ __launch_bounds__(128) void k_halt(const float* __restrict__ inputs,
        const float* __restrict__ hW, const float* __restrict__ hB,
        float* __restrict__ ws)
{
    __shared__ float hw[H];
    __shared__ float red[128];
    const int f = blockIdx.x, t = threadIdx.x;
    for (int i = t; i < H; i += 128) hw[i] = hW[i];
    __syncthreads();
    const float* row = inputs + (size_t)(f*P + t)*H;
    float acc = hB[0];
    for (int i = 0; i < H; i++) acc = fmaf(row[i], hw[i], acc);
    red[t] = 1.f/(1.f + __expf(-acc));
    __syncthreads();
    for (int s = 64; s > 0; s >>= 1){ if (t < s) red[t] += red[t+s]; __syncthreads(); }
    if (t == 0){
        float pf = red[0] * (1.f/P);
        float pt = ws[OF_PTN + f], rt = ws[OF_RT + f];
        float run  = (pt < 1.f) ? 1.f : 0.f;
        float cond = (pt + pf*run > 0.99f) ? 1.f : 0.f;
        float nh   = cond*run;
        run = (1.f - cond)*run;
        pt += pf*run;
        rt += nh*(1.f - pt);
        pt += nh*rt;
        ws[OF_PTN + f] = pt; ws[OF_RT + f] = rt;
        ws[OF_W   + f] = pf*run + nh*rt;
    }
}

// ---------------------------------------------------------------------------
// fused QKV projection with window gather. fp32 in/weights, bf16 out.
// ---------------------------------------------------------------------------
__global__ __launch_bounds__(256) void k_qkv(const float* __restrict__ X,
        const float* __restrict__ Wq, const float* __restrict__ biasq,
        const float* __restrict__ Wk, const float* __restrict__ biask,
        const float* __restrict__ Wv, const float* __restrict__ biasv,
        bf16* __restrict__ qo, bf16* __restrict__ ko, bf16* __restrict__ vo,
        int SP, int S)
{
    __shared__ __align__(16) float As [16][68];
    __shared__ __align__(16) float BsQ[16][68];
    __shared__ __align__(16) float BsK[16][68];
    __shared__ __align__(16) float BsV[16][68];
    const int tid = threadIdx.x;
    const int m0 = blockIdx.x*64, n0 = blockIdx.y*64;
    const int tx = tid & 15, ty = tid >> 4;
    const int am = tid >> 2, akk = (tid & 3) << 2;
    const int gm = m0 + am;
    const int w  = gm / S;
    const float* arow = X + (size_t)(gm - w*SP) * H;
    const int bkk = tid >> 4, bn = (tid & 15) << 2;

    float acc[3][4][4];
#pragma unroll
    for (int m=0;m<3;m++)
#pragma unroll
      for (int i=0;i<4;i++)
#pragma unroll
        for (int j=0;j<4;j++) acc[m][i][j] = 0.f;

    for (int k0 = 0; k0 < H; k0 += 16){
        float4 av = *(const float4*)(arow + k0 + akk);
        const size_t wofs = (size_t)(k0 + bkk)*H + n0 + bn;
        float4 fq = *(const float4*)(Wq + wofs);
        float4 fk = *(const float4*)(Wk + wofs);
        float4 fv = *(const float4*)(Wv + wofs);
        As[akk+0][am]=av.x; As[akk+1][am]=av.y; As[akk+2][am]=av.z; As[akk+3][am]=av.w;
        *(float4*)&BsQ[bkk][bn] = fq;
        *(float4*)&BsK[bkk][bn] = fk;
        *(float4*)&BsV[bkk][bn] = fv;
        __syncthreads();
#pragma unroll
        for (int kk = 0; kk < 16; ++kk){
            const float4 a4 = *(const float4*)&As [kk][ty<<2];
            const float4 q4 = *(const float4*)&BsQ[kk][tx<<2];
            const float4 k4 = *(const float4*)&BsK[kk][tx<<2];
            const float4 v4 = *(const float4*)&BsV[kk][tx<<2];
            const float aa[4]={a4.x,a4.y,a4.z,a4.w};
            const float qq[4]={q4.x,q4.y,q4.z,q4.w};
            const float kv[4]={k4.x,k4.y,k4.z,k4.w};
            const float vv[4]={v4.x,v4.y,v4.z,v4.w};
#pragma unroll
            for (int i=0;i<4;i++)
#pragma unroll
              for (int j=0;j<4;j++){
                acc[0][i][j] = fmaf(aa[i], qq[j], acc[0][i][j]);
                acc[1][i][j] = fmaf(aa[i], kv[j], acc[1][i][j]);
                acc[2][i][j] = fmaf(aa[i], vv[j], acc[2][i][j]);
              }
        }
        __syncthreads();
    }
    const int orow = m0 + (ty<<2);
    const int ocol = n0 + (tx<<2);
    float bqv[4], bkv[4], bvv[4];
#pragma unroll
    for (int j=0;j<4;j++){ bqv[j]=biasq[ocol+j]; bkv[j]=biask[ocol+j]; bvv[j]=biasv[ocol+j]; }
#pragma unroll
    for (int i=0;i<4;i++){
        ushort4 rq, rk, rv;
        rq.x=f2bu(acc[0][i][0]+bqv[0]); rq.y=f2bu(acc[0][i][1]+bqv[1]);
        rq.z=f2bu(acc[0][i][2]+bqv[2]); rq.w=f2bu(acc[0][i][3]+bqv[3]);
        rk.x=f2bu(acc[1][i][0]+bkv[0]); rk.y=f2bu(acc[1][i][1]+bkv[1]);
        rk.z=f2bu(acc[1][i][2]+bkv[2]); rk.w=f2bu(acc[1][i][3]+bkv[3]);
        rv.x=f2bu(acc[2][i][0]+bvv[0]); rv.y=f2bu(acc[2][i][1]+bvv[1]);
        rv.z=f2bu(acc[2][i][2]+bvv[2]); rv.w=f2bu(acc[2][i][3]+bvv[3]);
        *(ushort4*)(qo + (size_t)(orow+i)*H + ocol) = rq;
        *(ushort4*)(ko + (size_t)(orow+i)*H + ocol) = rk;
        *(ushort4*)(vo + (size_t)(orow+i)*H + ocol) = rv;
    }
}

// ---------------------------------------------------------------------------
// MFMA flash attention. Block = 4 waves, one (w, h, 64-q-row tile).
// Wave handles 16 q-rows. Scores computed TRANSPOSED (S^T = K·Q^T) so the
// C-frag column index (lane&15) is the q-row: softmax m/l/alpha are per-lane
// scalars. Two 16-k score tiles per step share one online-softmax update.
// PV path A: mfma_f32_16x16x16bf16_1k — exp'd S^T C-frag (k=quad*4+r) IS the
// K=16 B-operand layout, no data movement. Path B (fallback): 8 __shfl's
// reformat the two C-frags into one K=32 B-frag for mfma_f32_16x16x32_bf16.
// V staged transposed (V^T) in LDS per 128-k chunk; O accumulated as O^T.
// ---------------------------------------------------------------------------
#if __has_builtin(__builtin_amdgcn_mfma_f32_16x16x16bf16_1k)
#define ATTN_HAVE_1K 1
#else
#define ATTN_HAVE_1K 0
#endif

__global__ __launch_bounds__(256) void k_attn_mfma(const bf16* __restrict__ qb,
        const bf16* __restrict__ kb, const bf16* __restrict__ vb,
        bf16* __restrict__ ob, int S, int nqt)
{
    __shared__ unsigned short VT[32][136];   // V^T chunk: 32 dims x 128 k (pad->16B rows)
    const int bid = blockIdx.x;
    const int qt = bid % nqt;
    const int rest = bid / nqt;
    const int h = rest % HEADS;
    const int w = rest / HEADS;
    const int tid = threadIdx.x;
    const int wave = tid >> 6;
    const int lane = tid & 63;
    const int lq   = lane & 15;          // this lane's q-row (and frag m/n idx)
    const int quad = lane >> 4;

    // Q B-frag: lane holds Q[qrow][quad*8 + j], j=0..7
    const int qrow = w*S + qt*64 + wave*16 + lq;
    const bf16* qptr = qb + (size_t)qrow*H + h*HD + quad*8;
    const s8v qf = *(const s8v*)qptr;

    const size_t kvbase = (size_t)(w*S)*H + (size_t)h*HD;
    const float SC = 0.17677669529663687f;   // 1/sqrt(32)

    float m = -3e38f, l = 0.f;
    f4v o0 = {0.f,0.f,0.f,0.f}, o1 = {0.f,0.f,0.f,0.f};

    const int nch = S >> 7;                  // chunks of 128 k-rows
    for (int ch = 0; ch < nch; ++ch){
        __syncthreads();                     // prior chunk fully consumed
        {   // stage V^T: thread t -> k-row (t>>1), dims (t&1)*16 .. +15
            const int kr = tid >> 1, dp = (tid & 1) << 4;
            const bf16* vsrc = vb + kvbase + (size_t)(ch*128 + kr)*H + dp;
            uint4 a = *(const uint4*)vsrc;
            uint4 b = *(const uint4*)(vsrc + 8);
            unsigned short va[16];
            *(uint4*)&va[0] = a; *(uint4*)&va[8] = b;
#pragma unroll
            for (int i = 0; i < 16; ++i) VT[dp + i][kr] = va[i];
        }
        __syncthreads();
#pragma unroll
        for (int tt = 0; tt < 4; ++tt){      // 32 k-rows per step
            const int k0 = ch*128 + tt*32;
            const bf16* kptr0 = kb + kvbase + (size_t)(k0 + lq)*H + quad*8;
            const s8v kf0 = *(const s8v*)kptr0;
            const s8v kf1 = *(const s8v*)(kptr0 + 16*H);
            f4v st0 = {0.f,0.f,0.f,0.f}, st1 = {0.f,0.f,0.f,0.f};
            st0 = __builtin_amdgcn_mfma_f32_16x16x32_bf16(kf0, qf, st0, 0, 0, 0);
            st1 = __builtin_amdgcn_mfma_f32_16x16x32_bf16(kf1, qf, st1, 0, 0, 0);
            // lane holds S^T[k0 + quad*4 + r (+16 for st1)][q=lq]
            float s0=st0[0]*SC, s1=st0[1]*SC, s2=st0[2]*SC, s3=st0[3]*SC;
            float s4=st1[0]*SC, s5=st1[1]*SC, s6=st1[2]*SC, s7=st1[3]*SC;
            float mc = fmaxf(fmaxf(fmaxf(s0,s1),fmaxf(s2,s3)),
                             fmaxf(fmaxf(s4,s5),fmaxf(s6,s7)));
            mc = fmaxf(mc, __shfl_xor(mc, 16));
            mc = fmaxf(mc, __shfl_xor(mc, 32));
            const float mn = fmaxf(m, mc);
            const float alpha = __expf(m - mn);
            const float e0=__expf(s0-mn), e1=__expf(s1-mn), e2=__expf(s2-mn), e3=__expf(s3-mn);
            const float e4=__expf(s4-mn), e5=__expf(s5-mn), e6=__expf(s6-mn), e7=__expf(s7-mn);
            float ls = ((e0+e1)+(e2+e3)) + ((e4+e5)+(e6+e7));
            ls += __shfl_xor(ls, 16);
            ls += __shfl_xor(ls, 32);
            l = l*alpha + ls;
            m = mn;
            o0 = o0 * alpha;
            o1 = o1 * alpha;
            const int t32 = tt*32;
#if ATTN_HAVE_1K
            union { unsigned int u[2]; s4v v; } pf0, pf1;
            pf0.u[0] = pk2(e0,e1); pf0.u[1] = pk2(e2,e3);
            pf1.u[0] = pk2(e4,e5); pf1.u[1] = pk2(e6,e7);
            const s4v va00 = *(const s4v*)&VT[lq     ][t32      + (quad<<2)];
            const s4v va01 = *(const s4v*)&VT[lq     ][t32 + 16 + (quad<<2)];
            const s4v va10 = *(const s4v*)&VT[lq + 16][t32      + (quad<<2)];
            const s4v va11 = *(const s4v*)&VT[lq + 16][t32 + 16 + (quad<<2)];
            o0 = __builtin_amdgcn_mfma_f32_16x16x16bf16_1k(va00, pf0.v, o0, 0, 0, 0);
            o0 = __builtin_amdgcn_mfma_f32_16x16x16bf16_1k(va01, pf1.v, o0, 0, 0, 0);
            o1 = __builtin_amdgcn_mfma_f32_16x16x16bf16_1k(va10, pf0.v, o1, 0, 0, 0);
            o1 = __builtin_amdgcn_mfma_f32_16x16x16bf16_1k(va11, pf1.v, o1, 0, 0, 0);
#else
            // reformat two C-frags -> one K=32 B-frag via 8 shfls.
            // target lane (lq, quad) element j holds k = 8*quad + j; sources:
            // quads (2q)&3 / (2q+1)&3, tile = lo for quad<2 else hi.
            const unsigned int p0x = pk2(e0,e1), p0y = pk2(e2,e3);
            const unsigned int p1x = pk2(e4,e5), p1y = pk2(e6,e7);
            const int srcA = lq + ((( quad<<1)      & 3) << 4);
            const int srcB = lq + ((((quad<<1) | 1) & 3) << 4);
            const unsigned int a0 = (unsigned int)__shfl((int)p0x, srcA);
            const unsigned int a1 = (unsigned int)__shfl((int)p0y, srcA);
            const unsigned int a2 = (unsigned int)__shfl((int)p0x, srcB);
            const unsigned int a3 = (unsigned int)__shfl((int)p0y, srcB);
            const unsigned int b0 = (unsigned int)__shfl((int)p1x, srcA);
            const unsigned int b1 = (unsigned int)__shfl((int)p1y, srcA);
            const unsigned int b2 = (unsigned int)__shfl((int)p1x, srcB);
            const unsigned int b3 = (unsigned int)__shfl((int)p1y, srcB);
            const bool hi = (quad >= 2);
            union { unsigned int u[4]; s8v v; } bfr;
            bfr.u[0] = hi ? b0 : a0; bfr.u[1] = hi ? b1 : a1;
            bfr.u[2] = hi ? b2 : a2; bfr.u[3] = hi ? b3 : a3;
            const s8v va0 = *(const s8v*)&VT[lq     ][t32 + (quad<<3)];
            const s8v va1 = *(const s8v*)&VT[lq + 16][t32 + (quad<<3)];
            o0 = __builtin_amdgcn_mfma_f32_16x16x32_bf16(va0, bfr.v, o0, 0, 0, 0);
            o1 = __builtin_amdgcn_mfma_f32_16x16x32_bf16(va1, bfr.v, o1, 0, 0, 0);
#endif
        }
    }
    // epilogue: lane holds O^T[d = quad*4+r (+16)][q = lq] -> out[qrow][d]
    const float inv = 1.f / l;
    bf16* op = ob + (size_t)qrow*H + h*HD;
    *(unsigned int*)(op + quad*4)          = pk2(o0[0]*inv, o0[1]*inv);
    *(unsigned int*)(op + quad*4 + 2)      = pk2(o0[2]*inv, o0[3]*inv);
    *(unsigned int*)(op + 16 + quad*4)     = pk2(o1[0]*inv, o1[1]*inv);
    *(unsigned int*)(op + 16 + quad*4 + 2) = pk2(o1[2]*inv, o1[3]*inv);
}

// ---------------------------------------------------------------------------
// output projection + overlap-add accumulate: atomicAdd 0.25*(y+bo)/cnt into g
// ---------------------------------------------------------------------------
__global__ __launch_bounds__(256) void k_oproj(const bf16* __restrict__ X,
        const float* __restrict__ W, const float* __restrict__ bias,
        float* __restrict__ g, int S, int nw)
{
    __shared__ __align__(16) float As[16][68];
    __shared__ __align__(16) float Bs[16][68];
    const int tid = threadIdx.x;
    const int m0 = blockIdx.x*64, n0 = blockIdx.y*64;
    const int tx = tid & 15, ty = tid >> 4;
    const int am = tid >> 2, akk = (tid & 3) << 2;
    const bf16* arow = X + (size_t)(m0 + am) * H;
    const int bkk = tid >> 4, bn = (tid & 15) << 2;
    float acc[4][4];
#pragma unroll
    for (int i=0;i<4;i++)
#pragma unroll
      for (int j=0;j<4;j++) acc[i][j] = 0.f;

    for (int k0 = 0; k0 < H; k0 += 16){
        ushort4 aw = *(const ushort4*)(arow + k0 + akk);
        float4 fb = *(const float4*)(W + (size_t)(k0 + bkk)*H + n0 + bn);
        As[akk+0][am]=bu2f(aw.x); As[akk+1][am]=bu2f(aw.y);
        As[akk+2][am]=bu2f(aw.z); As[akk+3][am]=bu2f(aw.w);
        *(float4*)&Bs[bkk][bn] = fb;
        __syncthreads();
#pragma unroll
        for (int kk = 0; kk < 16; ++kk){
            const float4 a4 = *(const float4*)&As[kk][ty<<2];
            const float4 b4 = *(const float4*)&Bs[kk][tx<<2];
            const float aa[4]={a4.x,a4.y,a4.z,a4.w};
            const float bb[4]={b4.x,b4.y,b4.z,b4.w};
#pragma unroll
            for (int i=0;i<4;i++)
#pragma unroll
              for (int j=0;j<4;j++) acc[i][j] = fmaf(aa[i], bb[j], acc[i][j]);
        }
        __syncthreads();
    }
    const int orow = m0 + (ty<<2);
    const int ocol = n0 + (tx<<2);
    const int s = S >> 7;
    float bv[4];
#pragma unroll
    for (int j=0;j<4;j++) bv[j] = bias[ocol+j];
#pragma unroll
    for (int i=0;i<4;i++){
        const int gm = orow + i;
        const int w = gm / S;
        const int pos = gm - w*S;
        const int f = w + (pos >> 7);
        const int p = pos & 127;
        const int cnt = imin(nw-1, f) - imax(0, f - s + 1) + 1;
        const float scl = 0.25f / (float)cnt;
        float* dst = g + (size_t)(f*P + p)*H + ocol;
        atomicAdd(dst+0, (acc[i][0]+bv[0])*scl);
        atomicAdd(dst+1, (acc[i][1]+bv[1])*scl);
        atomicAdd(dst+2, (acc[i][2]+bv[2])*scl);
        atomicAdd(dst+3, (acc[i][3]+bv[3])*scl);
    }
}

// ---------------------------------------------------------------------------
// transition: inputs <- g (temporal); context <- g*w + context*(1-w)
// ---------------------------------------------------------------------------
__global__ __launch_bounds__(256) void k_transition(const float* __restrict__ g,
        const float* __restrict__ ws, float* __restrict__ inputs,
        float* __restrict__ context)
{
    const int idx = blockIdx.x*256 + threadIdx.x;
    const int f = idx >> 15;          // /(P*H)=32768
    const float tval = g[idx];
    const float wf = ws[OF_W + f];
    inputs[idx] = tval;
    context[idx] = tval*wf + context[idx]*(1.f - wf);
}

// ---------------------------------------------------------------------------
// reduce context over all rows -> osum[256]
// ---------------------------------------------------------------------------
__global__ __launch_bounds__(256) void k_reduce(const float* __restrict__ context,
        float* __restrict__ osum)
{
    const int hcol = threadIdx.x;
    const float* base = context + (size_t)blockIdx.x * 64 * H;
    float s = 0.f;
#pragma unroll 8
    for (int r = 0; r < 64; ++r) s += base[(size_t)r*H + hcol];
    atomicAdd(&osum[hcol], s);
}

// ---------------------------------------------------------------------------
// classes = osum @ cls_W + cls_b  (softmax-row-sum identity kills marginal)
// ---------------------------------------------------------------------------
__global__ __launch_bounds__(256) void k_classes(const float* __restrict__ ws,
        void* __restrict__ out)
{
    __shared__ float os[H];
    const int tid = threadIdx.x;
    os[tid] = ws[OF_OSUM + tid];
    __syncthreads();
    const int n = blockIdx.x*256 + tid;
    if (n < NCLS){
        const float* clsW = ws + OF_WTS + WO_CLSW;
        float acc = ws[OF_WTS + WO_CLSB + n];
        for (int hh = 0; hh < H; ++hh) acc = fmaf(os[hh], clsW[(size_t)hh*NCLS + n], acc);
        if (ws[OF_FLAG] != 0.f) ((bf16*)out)[n] = __float2bfloat16(acc);
        else                    ((float*)out)[n] = acc;
    }
}

// ---------------------------------------------------------------------------
extern "C" void kernel_launch(void* const* d_in, const int* in_sizes, int n_in,
                              void* d_out, int out_size, void* d_ws, size_t ws_size,
                              hipStream_t stream)
{
    (void)in_sizes; (void)n_in; (void)out_size; (void)ws_size;
    float* WS = (float*)d_ws;
    float* context = WS + OF_CTX;
    float* g       = WS + OF_G;
    float* inputs  = WS + OF_INP;
    float* wts     = WS + OF_WTS;
    bf16*  qb      = (bf16*)(wts + WTS_TOTAL);
    bf16*  kb      = qb + QKV_ELEMS;
    bf16*  vb      = kb + QKV_ELEMS;
    // total ws: (512 + 3*FPH + WTS_TOTAL)*4 + 3*QKV_ELEMS*2 ≈ 26.2 MB

    (void)hipMemsetAsync(WS, 0, (size_t)(OF_INP)*4, stream);
    k_detect<<<1, 256, 0, stream>>>((const unsigned int*)d_in[0], WS);

    ConvArgs ca;
    const int srcs[13] = {0, 3, 4, 8, 9, 10, 12, 14, 16, 11, 13, 15, 17};
    const int offs[13] = {OF_INP,
        OF_WTS+WO_HALTW, OF_WTS+WO_HALTB, OF_WTS+WO_CLSW, OF_WTS+WO_CLSB,
        OF_WTS+WO_WQ, OF_WTS+WO_WK, OF_WTS+WO_WV, OF_WTS+WO_WO,
        OF_WTS+WO_BQ, OF_WTS+WO_BK, OF_WTS+WO_BV, OF_WTS+WO_BO};
    const int ns[13]  = {FPH, H, 1, H*NCLS, NCLS,
        3*H*H, 3*H*H, 3*H*H, 3*H*H, 3*H, 3*H, 3*H, 3*H};
    int total = 0;
    for (int t = 0; t < 13; ++t){ ca.src[t] = d_in[srcs[t]]; ca.off[t] = offs[t]; ca.n[t] = ns[t]; total += ns[t]; }
    k_convert<<<(total + 255)/256, 256, 0, stream>>>(ca, WS);

    const int scales[3] = {2, 4, 6};
    for (int it = 0; it < 2; ++it){
        k_halt<<<F, 128, 0, stream>>>(inputs, wts + WO_HALTW, wts + WO_HALTB, WS);
        (void)hipMemsetAsync(g, 0, (size_t)FPH*4, stream);
        for (int i = 0; i < 3; ++i){
            const int s = scales[i];
            const int nw = F - s + 1;
            const int S = s*P;
            const int tokens = nw*S;
            const size_t woff = (size_t)i*H*H;
            const size_t boff = (size_t)i*H;
            k_qkv<<<dim3(tokens/64, H/64), 256, 0, stream>>>(inputs,
                wts+WO_WQ+woff, wts+WO_BQ+boff, wts+WO_WK+woff, wts+WO_BK+boff,
                wts+WO_WV+woff, wts+WO_BV+boff, qb, kb, vb, (s-1)*P, S);
            k_attn_mfma<<<nw*HEADS*(S/64), 256, 0, stream>>>(qb, kb, vb, qb, S, S/64);
            k_oproj<<<dim3(tokens/64, H/64), 256, 0, stream>>>(qb,
                wts+WO_WO+woff, wts+WO_BO+boff, g, S, nw);
        }
        k_transition<<<FPH/256, 256, 0, stream>>>(g, WS, inputs, context);
    }
    k_reduce<<<(F*P)/64, 256, 0, stream>>>(context, WS + OF_OSUM);
    k_classes<<<3, 256, 0, stream>>>(WS, d_out);
}

// Round 5
// 534.951 us; speedup vs baseline: 3.0463x; 1.5436x over previous
//
#include <hip/hip_runtime.h>
#include <hip/hip_bf16.h>

typedef __hip_bfloat16 bf16;

#define F 18
#define P 128
#define H 256
#define HEADS 8
#define HD 32
#define NCLS 625
#define FPH (F*P*H)

// ---- fp32 workspace layout (float slots from base) ----
#define OF_FLAG   0
#define OF_PTN    16
#define OF_RT     48
#define OF_W      80
#define OF_OSUM   128
#define OF_CTX    512
#define OF_G      (OF_CTX + FPH)       // 590336
#define OF_INP    (OF_G + FPH)        // 1180160
#define OF_FW     (OF_INP + FPH)      // 1769984
#define WO2_HALTW 0
#define WO2_HALTB 256
#define WO2_CLSB  272
#define WO2_CLSW  912
#define WO2_BQ    160912
#define WO2_BK    161680
#define WO2_BV    162448
#define WO2_BO    163216
#define FW_TOTAL  163984
#define NF_TOTAL  (OF_FW + FW_TOTAL)  // 1933968 floats

// ---- bf16 workspace layout (bf16 slots after fp32 area) ----
#define BB_WQT 0
#define BB_WKT 196608
#define BB_WVT 393216
#define BB_WOT 589824
#define BB_INP 786432
#define BB_QB  1376256
#define QKV_ELEMS 2555904   // 9984*256
#define BB_KB  (BB_QB + QKV_ELEMS)
#define BB_VB  (BB_KB + QKV_ELEMS)

typedef __attribute__((ext_vector_type(8))) short s8v;   // A/B frag, 16x16x32 bf16
typedef __attribute__((ext_vector_type(4))) short s4v;   // A/B frag, 16x16x16 bf16
typedef __attribute__((ext_vector_type(4))) float f4v;   // C/D frag

__device__ __forceinline__ float b2f(bf16 x){ return __bfloat162float(x); }
__device__ __forceinline__ unsigned short f2bu(float x){
    union { __hip_bfloat16 h; unsigned short u; } cv; cv.h = __float2bfloat16(x); return cv.u;
}
__device__ __forceinline__ unsigned int pk2(float a, float b){
    return (unsigned int)f2bu(a) | ((unsigned int)f2bu(b) << 16);
}
__device__ __forceinline__ int imin(int a,int b){ return a<b?a:b; }
__device__ __forceinline__ int imax(int a,int b){ return a>b?a:b; }

// ---------------------------------------------------------------------------
// dtype probe (low 16 bits exponent histogram): bf16 vs fp32 input buffers
// ---------------------------------------------------------------------------
__global__ __launch_bounds__(256) void k_detect(const unsigned int* __restrict__ embw,
                                                float* __restrict__ ws)
{
    __shared__ int cnt;
    if (threadIdx.x == 0) cnt = 0;
    __syncthreads();
    int c = 0;
    for (int i = threadIdx.x; i < 512; i += 256){
        unsigned int e = (embw[i] >> 7) & 0xffu;
        if (e >= 120u && e <= 130u) c++;
    }
    atomicAdd(&cnt, c);
    __syncthreads();
    if (threadIdx.x == 0) ws[OF_FLAG] = (cnt > 256) ? 1.f : 0.f;
}

// ---------------------------------------------------------------------------
// convert: mode 0 = fp32 copy; mode 1 = bf16 transposed weight (3x256x256);
// mode 2 = embed dual-write (fp32 inputs + bf16 mirror)
// ---------------------------------------------------------------------------
struct ConvArgs {
    const void* src[13];
    int mode[13];
    int n[13];
    int off[13];
};
__global__ __launch_bounds__(256) void k_convert(ConvArgs a, float* __restrict__ ws,
                                                 bf16* __restrict__ bb)
{
    int gid = blockIdx.x*256 + threadIdx.x;
    const int isbf = (ws[OF_FLAG] != 0.f);
#pragma unroll
    for (int t = 0; t < 13; ++t){
        if (gid < a.n[t]){
            float v = isbf ? b2f(((const bf16*)a.src[t])[gid])
                           : ((const float*)a.src[t])[gid];
            if (a.mode[t] == 0){
                ws[a.off[t] + gid] = v;
            } else if (a.mode[t] == 1){
                const int i = gid >> 16, rem = gid & 65535;
                const int k = rem >> 8, nn = rem & 255;
                bb[a.off[t] + (i << 16) + (nn << 8) + k] = __float2bfloat16(v);
            } else {
                ws[OF_INP + gid] = v;
                bb[BB_INP + gid] = __float2bfloat16(v);
            }
            return;
        }
        gid -= a.n[t];
    }
}

// ---------------------------------------------------------------------------
// halting probability + ACT state update (one block per frame)
// ---------------------------------------------------------------------------
__global__ __launch_bounds__(128) void k_halt(const float* __restrict__ inputs,
        const float* __restrict__ hW, const float* __restrict__ hB,
        float* __restrict__ ws)
{
    __shared__ float hw[H];
    __shared__ float red[128];
    const int f = blockIdx.x, t = threadIdx.x;
    for (int i = t; i < H; i += 128) hw[i] = hW[i];
    __syncthreads();
    const float* row = inputs + (size_t)(f*P + t)*H;
    float acc = hB[0];
    for (int i = 0; i < H; i++) acc = fmaf(row[i], hw[i], acc);
    red[t] = 1.f/(1.f + __expf(-acc));
    __syncthreads();
    for (int s = 64; s > 0; s >>= 1){ if (t < s) red[t] += red[t+s]; __syncthreads(); }
    if (t == 0){
        float pf = red[0] * (1.f/P);
        float pt = ws[OF_PTN + f], rt = ws[OF_RT + f];
        float run  = (pt < 1.f) ? 1.f : 0.f;
        float cond = (pt + pf*run > 0.99f) ? 1.f : 0.f;
        float nh   = cond*run;
        run = (1.f - cond)*run;
        pt += pf*run;
        rt += nh*(1.f - pt);
        pt += nh*rt;
        ws[OF_PTN + f] = pt; ws[OF_RT + f] = rt;
        ws[OF_W   + f] = pf*run + nh*rt;
    }
}

// ---------------------------------------------------------------------------
// MFMA QKV projection, LDS-free. Block: 64 tokens x 64 cols, 4 waves.
// Wave owns 16-col slice (n0), 4 m-tiles. A-frag: X[m0+lq][k0+quad*8..]
// (window gather folded into row pointer). B-frag: W^T[n0+lq][k0+quad*8..].
// D: lane reg r = C[m-tile row quad*4+r][n0+lq].
// ---------------------------------------------------------------------------
__global__ __launch_bounds__(256) void k_qkv_mfma(const bf16* __restrict__ X,
        const bf16* __restrict__ WqT, const bf16* __restrict__ WkT,
        const bf16* __restrict__ WvT,
        const float* __restrict__ bq, const float* __restrict__ bk,
        const float* __restrict__ bv,
        bf16* __restrict__ qo, bf16* __restrict__ ko, bf16* __restrict__ vo,
        int SP, int S)
{
    const int tid = threadIdx.x;
    const int wave = tid >> 6, lane = tid & 63;
    const int lq = lane & 15, quad = lane >> 4;
    const int m0 = blockIdx.x * 64;
    const int n0 = blockIdx.y * 64 + wave * 16;

    const bf16* arow[4];
#pragma unroll
    for (int mt = 0; mt < 4; ++mt){
        const int gm = m0 + mt*16 + lq;
        const int w  = gm / S;
        arow[mt] = X + (size_t)(gm - w*SP)*H + quad*8;
    }
    const bf16* bqp = WqT + (size_t)(n0 + lq)*H + quad*8;
    const bf16* bkp = WkT + (size_t)(n0 + lq)*H + quad*8;
    const bf16* bvp = WvT + (size_t)(n0 + lq)*H + quad*8;

    f4v aq[4], ak[4], av[4];
#pragma unroll
    for (int mt = 0; mt < 4; ++mt){
        aq[mt] = (f4v){0.f,0.f,0.f,0.f};
        ak[mt] = (f4v){0.f,0.f,0.f,0.f};
        av[mt] = (f4v){0.f,0.f,0.f,0.f};
    }
#pragma unroll
    for (int k0 = 0; k0 < H; k0 += 32){
        const s8v bfq = *(const s8v*)(bqp + k0);
        const s8v bfk = *(const s8v*)(bkp + k0);
        const s8v bfv = *(const s8v*)(bvp + k0);
#pragma unroll
        for (int mt = 0; mt < 4; ++mt){
            const s8v af = *(const s8v*)(arow[mt] + k0);
            aq[mt] = __builtin_amdgcn_mfma_f32_16x16x32_bf16(af, bfq, aq[mt], 0, 0, 0);
            ak[mt] = __builtin_amdgcn_mfma_f32_16x16x32_bf16(af, bfk, ak[mt], 0, 0, 0);
            av[mt] = __builtin_amdgcn_mfma_f32_16x16x32_bf16(af, bfv, av[mt], 0, 0, 0);
        }
    }
    const float bqv = bq[n0 + lq], bkv = bk[n0 + lq], bvv = bv[n0 + lq];
#pragma unroll
    for (int mt = 0; mt < 4; ++mt){
#pragma unroll
        for (int r = 0; r < 4; ++r){
            const size_t row = (size_t)(m0 + mt*16 + quad*4 + r)*H + n0 + lq;
            qo[row] = __float2bfloat16(aq[mt][r] + bqv);
            ko[row] = __float2bfloat16(ak[mt][r] + bkv);
            vo[row] = __float2bfloat16(av[mt][r] + bvv);
        }
    }
}

// ---------------------------------------------------------------------------
// MFMA flash attention (unchanged from round-4 passing version).
// ---------------------------------------------------------------------------
#if __has_builtin(__builtin_amdgcn_mfma_f32_16x16x16bf16_1k)
#define ATTN_HAVE_1K 1
#else
#define ATTN_HAVE_1K 0
#endif

__global__ __launch_bounds__(256) void k_attn_mfma(const bf16* __restrict__ qb,
        const bf16* __restrict__ kb, const bf16* __restrict__ vb,
        bf16* __restrict__ ob, int S, int nqt)
{
    __shared__ unsigned short VT[32][136];
    const int bid = blockIdx.x;
    const int qt = bid % nqt;
    const int rest = bid / nqt;
    const int h = rest % HEADS;
    const int w = rest / HEADS;
    const int tid = threadIdx.x;
    const int wave = tid >> 6;
    const int lane = tid & 63;
    const int lq   = lane & 15;
    const int quad = lane >> 4;

    const int qrow = w*S + qt*64 + wave*16 + lq;
    const bf16* qptr = qb + (size_t)qrow*H + h*HD + quad*8;
    const s8v qf = *(const s8v*)qptr;

    const size_t kvbase = (size_t)(w*S)*H + (size_t)h*HD;
    const float SC = 0.17677669529663687f;

    float m = -3e38f, l = 0.f;
    f4v o0 = {0.f,0.f,0.f,0.f}, o1 = {0.f,0.f,0.f,0.f};

    const int nch = S >> 7;
    for (int ch = 0; ch < nch; ++ch){
        __syncthreads();
        {
            const int kr = tid >> 1, dp = (tid & 1) << 4;
            const bf16* vsrc = vb + kvbase + (size_t)(ch*128 + kr)*H + dp;
            uint4 a = *(const uint4*)vsrc;
            uint4 b = *(const uint4*)(vsrc + 8);
            unsigned short va[16];
            *(uint4*)&va[0] = a; *(uint4*)&va[8] = b;
#pragma unroll
            for (int i = 0; i < 16; ++i) VT[dp + i][kr] = va[i];
        }
        __syncthreads();
#pragma unroll
        for (int tt = 0; tt < 4; ++tt){
            const int k0 = ch*128 + tt*32;
            const bf16* kptr0 = kb + kvbase + (size_t)(k0 + lq)*H + quad*8;
            const s8v kf0 = *(const s8v*)kptr0;
            const s8v kf1 = *(const s8v*)(kptr0 + 16*H);
            f4v st0 = {0.f,0.f,0.f,0.f}, st1 = {0.f,0.f,0.f,0.f};
            st0 = __builtin_amdgcn_mfma_f32_16x16x32_bf16(kf0, qf, st0, 0, 0, 0);
            st1 = __builtin_amdgcn_mfma_f32_16x16x32_bf16(kf1, qf, st1, 0, 0, 0);
            float s0=st0[0]*SC, s1=st0[1]*SC, s2=st0[2]*SC, s3=st0[3]*SC;
            float s4=st1[0]*SC, s5=st1[1]*SC, s6=st1[2]*SC, s7=st1[3]*SC;
            float mc = fmaxf(fmaxf(fmaxf(s0,s1),fmaxf(s2,s3)),
                             fmaxf(fmaxf(s4,s5),fmaxf(s6,s7)));
            mc = fmaxf(mc, __shfl_xor(mc, 16));
            mc = fmaxf(mc, __shfl_xor(mc, 32));
            const float mn = fmaxf(m, mc);
            const float alpha = __expf(m - mn);
            const float e0=__expf(s0-mn), e1=__expf(s1-mn), e2=__expf(s2-mn), e3=__expf(s3-mn);
            const float e4=__expf(s4-mn), e5=__expf(s5-mn), e6=__expf(s6-mn), e7=__expf(s7-mn);
            float ls = ((e0+e1)+(e2+e3)) + ((e4+e5)+(e6+e7));
            ls += __shfl_xor(ls, 16);
            ls += __shfl_xor(ls, 32);
            l = l*alpha + ls;
            m = mn;
            o0 = o0 * alpha;
            o1 = o1 * alpha;
            const int t32 = tt*32;
#if ATTN_HAVE_1K
            union { unsigned int u[2]; s4v v; } pf0, pf1;
            pf0.u[0] = pk2(e0,e1); pf0.u[1] = pk2(e2,e3);
            pf1.u[0] = pk2(e4,e5); pf1.u[1] = pk2(e6,e7);
            const s4v va00 = *(const s4v*)&VT[lq     ][t32      + (quad<<2)];
            const s4v va01 = *(const s4v*)&VT[lq     ][t32 + 16 + (quad<<2)];
            const s4v va10 = *(const s4v*)&VT[lq + 16][t32      + (quad<<2)];
            const s4v va11 = *(const s4v*)&VT[lq + 16][t32 + 16 + (quad<<2)];
            o0 = __builtin_amdgcn_mfma_f32_16x16x16bf16_1k(va00, pf0.v, o0, 0, 0, 0);
            o0 = __builtin_amdgcn_mfma_f32_16x16x16bf16_1k(va01, pf1.v, o0, 0, 0, 0);
            o1 = __builtin_amdgcn_mfma_f32_16x16x16bf16_1k(va10, pf0.v, o1, 0, 0, 0);
            o1 = __builtin_amdgcn_mfma_f32_16x16x16bf16_1k(va11, pf1.v, o1, 0, 0, 0);
#else
            const unsigned int p0x = pk2(e0,e1), p0y = pk2(e2,e3);
            const unsigned int p1x = pk2(e4,e5), p1y = pk2(e6,e7);
            const int srcA = lq + ((( quad<<1)      & 3) << 4);
            const int srcB = lq + ((((quad<<1) | 1) & 3) << 4);
            const unsigned int a0 = (unsigned int)__shfl((int)p0x, srcA);
            const unsigned int a1 = (unsigned int)__shfl((int)p0y, srcA);
            const unsigned int a2 = (unsigned int)__shfl((int)p0x, srcB);
            const unsigned int a3 = (unsigned int)__shfl((int)p0y, srcB);
            const unsigned int b0 = (unsigned int)__shfl((int)p1x, srcA);
            const unsigned int b1 = (unsigned int)__shfl((int)p1y, srcA);
            const unsigned int b2 = (unsigned int)__shfl((int)p1x, srcB);
            const unsigned int b3 = (unsigned int)__shfl((int)p1y, srcB);
            const bool hi = (quad >= 2);
            union { unsigned int u[4]; s8v v; } bfr;
            bfr.u[0] = hi ? b0 : a0; bfr.u[1] = hi ? b1 : a1;
            bfr.u[2] = hi ? b2 : a2; bfr.u[3] = hi ? b3 : a3;
            const s8v va0 = *(const s8v*)&VT[lq     ][t32 + (quad<<3)];
            const s8v va1 = *(const s8v*)&VT[lq + 16][t32 + (quad<<3)];
            o0 = __builtin_amdgcn_mfma_f32_16x16x32_bf16(va0, bfr.v, o0, 0, 0, 0);
            o1 = __builtin_amdgcn_mfma_f32_16x16x32_bf16(va1, bfr.v, o1, 0, 0, 0);
#endif
        }
    }
    const float inv = 1.f / l;
    bf16* op = ob + (size_t)qrow*H + h*HD;
    *(unsigned int*)(op + quad*4)          = pk2(o0[0]*inv, o0[1]*inv);
    *(unsigned int*)(op + quad*4 + 2)      = pk2(o0[2]*inv, o0[3]*inv);
    *(unsigned int*)(op + 16 + quad*4)     = pk2(o1[0]*inv, o1[1]*inv);
    *(unsigned int*)(op + 16 + quad*4 + 2) = pk2(o1[2]*inv, o1[3]*inv);
}

// ---------------------------------------------------------------------------
// MFMA output projection + overlap-add atomicAdd into g. Same structure as
// k_qkv_mfma (1 matrix); epilogue maps token row -> (f,p), scales by
// 0.25/cnt and accumulates.
// ---------------------------------------------------------------------------
__global__ __launch_bounds__(256) void k_oproj_mfma(const bf16* __restrict__ X,
        const bf16* __restrict__ WT, const float* __restrict__ bias,
        float* __restrict__ g, int S, int nw)
{
    const int tid = threadIdx.x;
    const int wave = tid >> 6, lane = tid & 63;
    const int lq = lane & 15, quad = lane >> 4;
    const int m0 = blockIdx.x * 64;
    const int n0 = blockIdx.y * 64 + wave * 16;

    const bf16* arow[4];
#pragma unroll
    for (int mt = 0; mt < 4; ++mt)
        arow[mt] = X + (size_t)(m0 + mt*16 + lq)*H + quad*8;
    const bf16* bp = WT + (size_t)(n0 + lq)*H + quad*8;

    f4v acc[4];
#pragma unroll
    for (int mt = 0; mt < 4; ++mt) acc[mt] = (f4v){0.f,0.f,0.f,0.f};
#pragma unroll
    for (int k0 = 0; k0 < H; k0 += 32){
        const s8v bf_ = *(const s8v*)(bp + k0);
#pragma unroll
        for (int mt = 0; mt < 4; ++mt){
            const s8v af = *(const s8v*)(arow[mt] + k0);
            acc[mt] = __builtin_amdgcn_mfma_f32_16x16x32_bf16(af, bf_, acc[mt], 0, 0, 0);
        }
    }
    const float bv = bias[n0 + lq];
    const int s = S >> 7;
#pragma unroll
    for (int mt = 0; mt < 4; ++mt){
#pragma unroll
        for (int r = 0; r < 4; ++r){
            const int gm = m0 + mt*16 + quad*4 + r;
            const int w = gm / S;
            const int pos = gm - w*S;
            const int f = w + (pos >> 7);
            const int p = pos & 127;
            const int cnt = imin(nw-1, f) - imax(0, f - s + 1) + 1;
            const float scl = 0.25f / (float)cnt;
            atomicAdd(&g[(size_t)(f*P + p)*H + n0 + lq], (acc[mt][r] + bv)*scl);
        }
    }
}

// ---------------------------------------------------------------------------
// transition: inputs <- g (fp32 + bf16 mirror); context <- g*w + ctx*(1-w)
// ---------------------------------------------------------------------------
__global__ __launch_bounds__(256) void k_transition(const float* __restrict__ g,
        const float* __restrict__ ws, float* __restrict__ inputs,
        bf16* __restrict__ inpb, float* __restrict__ context)
{
    const int idx = blockIdx.x*256 + threadIdx.x;
    const int f = idx >> 15;
    const float tval = g[idx];
    const float wf = ws[OF_W + f];
    inputs[idx] = tval;
    inpb[idx] = __float2bfloat16(tval);
    context[idx] = tval*wf + context[idx]*(1.f - wf);
}

// ---------------------------------------------------------------------------
// reduce context over all rows -> osum[256]
// ---------------------------------------------------------------------------
__global__ __launch_bounds__(256) void k_reduce(const float* __restrict__ context,
        float* __restrict__ osum)
{
    const int hcol = threadIdx.x;
    const float* base = context + (size_t)blockIdx.x * 64 * H;
    float s = 0.f;
#pragma unroll 8
    for (int r = 0; r < 64; ++r) s += base[(size_t)r*H + hcol];
    atomicAdd(&osum[hcol], s);
}

// ---------------------------------------------------------------------------
// classes = osum @ cls_W + cls_b  (softmax-row-sum identity kills marginal)
// ---------------------------------------------------------------------------
__global__ __launch_bounds__(256) void k_classes(const float* __restrict__ ws,
        void* __restrict__ out)
{
    __shared__ float os[H];
    const int tid = threadIdx.x;
    os[tid] = ws[OF_OSUM + tid];
    __syncthreads();
    const int n = blockIdx.x*256 + tid;
    if (n < NCLS){
        const float* clsW = ws + OF_FW + WO2_CLSW;
        float acc = ws[OF_FW + WO2_CLSB + n];
        for (int hh = 0; hh < H; ++hh) acc = fmaf(os[hh], clsW[(size_t)hh*NCLS + n], acc);
        if (ws[OF_FLAG] != 0.f) ((bf16*)out)[n] = __float2bfloat16(acc);
        else                    ((float*)out)[n] = acc;
    }
}

// ---------------------------------------------------------------------------
extern "C" void kernel_launch(void* const* d_in, const int* in_sizes, int n_in,
                              void* d_out, int out_size, void* d_ws, size_t ws_size,
                              hipStream_t stream)
{
    (void)in_sizes; (void)n_in; (void)out_size; (void)ws_size;
    float* WS = (float*)d_ws;
    float* context = WS + OF_CTX;
    float* g       = WS + OF_G;
    float* inputs  = WS + OF_INP;
    float* fw      = WS + OF_FW;
    bf16*  bb      = (bf16*)(WS + NF_TOTAL);
    bf16*  inpb    = bb + BB_INP;
    bf16*  qb      = bb + BB_QB;
    bf16*  kb      = bb + BB_KB;
    bf16*  vb      = bb + BB_VB;
    // total ws ≈ 7.7 MB fp32 + 18.1 MB bf16 ≈ 25.8 MB

    (void)hipMemsetAsync(WS, 0, (size_t)OF_INP*4, stream);  // state+ctx+g
    k_detect<<<1, 256, 0, stream>>>((const unsigned int*)d_in[0], WS);

    ConvArgs ca;
    const int srcs[13]  = {0, 3, 4, 8, 9, 11, 13, 15, 17, 10, 12, 14, 16};
    const int modes[13] = {2, 0, 0, 0, 0, 0, 0, 0, 0, 1, 1, 1, 1};
    const int ns[13]    = {FPH, 256, 1, H*NCLS, NCLS, 768, 768, 768, 768,
                           196608, 196608, 196608, 196608};
    const int offs[13]  = {0,
        OF_FW+WO2_HALTW, OF_FW+WO2_HALTB, OF_FW+WO2_CLSW, OF_FW+WO2_CLSB,
        OF_FW+WO2_BQ, OF_FW+WO2_BK, OF_FW+WO2_BV, OF_FW+WO2_BO,
        BB_WQT, BB_WKT, BB_WVT, BB_WOT};
    int total = 0;
    for (int t = 0; t < 13; ++t){
        ca.src[t] = d_in[srcs[t]]; ca.mode[t] = modes[t];
        ca.n[t] = ns[t]; ca.off[t] = offs[t]; total += ns[t];
    }
    k_convert<<<(total + 255)/256, 256, 0, stream>>>(ca, WS, bb);

    const int scales[3] = {2, 4, 6};
    for (int it = 0; it < 2; ++it){
        k_halt<<<F, 128, 0, stream>>>(inputs, fw + WO2_HALTW, fw + WO2_HALTB, WS);
        (void)hipMemsetAsync(g, 0, (size_t)FPH*4, stream);
        for (int i = 0; i < 3; ++i){
            const int s = scales[i];
            const int nw = F - s + 1;
            const int S = s*P;
            const int tokens = nw*S;          // 4352 / 7680 / 9984
            const int wo = i << 16;           // 256*256 per scale
            const int bo = i * 256;
            k_qkv_mfma<<<dim3(tokens/64, 4), 256, 0, stream>>>(inpb,
                bb+BB_WQT+wo, bb+BB_WKT+wo, bb+BB_WVT+wo,
                fw+WO2_BQ+bo, fw+WO2_BK+bo, fw+WO2_BV+bo,
                qb, kb, vb, (s-1)*P, S);
            k_attn_mfma<<<nw*HEADS*(S/64), 256, 0, stream>>>(qb, kb, vb, qb, S, S/64);
            k_oproj_mfma<<<dim3(tokens/64, 4), 256, 0, stream>>>(qb,
                bb+BB_WOT+wo, fw+WO2_BO+bo, g, S, nw);
        }
        k_transition<<<FPH/256, 256, 0, stream>>>(g, WS, inputs, inpb, context);
    }
    k_reduce<<<(F*P)/64, 256, 0, stream>>>(context, WS + OF_OSUM);
    k_classes<<<3, 256, 0, stream>>>(WS, d_out);
}

// Round 6
// 431.502 us; speedup vs baseline: 3.7766x; 1.2397x over previous
//
#include <hip/hip_runtime.h>
#include <hip/hip_bf16.h>

typedef __hip_bfloat16 bf16;

#define F 18
#define P 128
#define H 256
#define HEADS 8
#define HD 32
#define NCLS 625
#define FPH (F*P*H)        // 589824
#define RPS 589824         // one scale's q/k/v/ao buffer: 2304 rows x 256

// ---- fp32 workspace layout (float slots) ----
#define OF_FLAG   0
#define OF_PTN    16
#define OF_RT     48
#define OF_W      80
#define OF_OSUM   128
#define OF_CTX    512
#define OF_AO     (OF_CTX + FPH)      // 590336 ; 3*RPS fp32 attn-out accum
#define OF_FW     (OF_AO + 3*RPS)     // 2359808
#define WO2_HALTW 0
#define WO2_HALTB 256
#define WO2_CLSB  272
#define WO2_CLSW  912
#define WO2_BQ    160912
#define WO2_BK    161680
#define WO2_BV    162448
#define WO2_BO    163216
#define FW_TOTAL  163984
#define NF_TOTAL  (OF_FW + FW_TOTAL)  // 2523792 floats

// ---- bf16 workspace layout (bf16 slots after fp32 area) ----
#define BB_WQT 0
#define BB_WKT 196608
#define BB_WVT 393216
#define BB_WOT 589824
#define BB_INP 786432
#define BB_QB  1376256
#define BB_KB  (BB_QB + 3*RPS)
#define BB_VB  (BB_KB + 3*RPS)
// total ws ~= 10.1 MB fp32 + 13.4 MB bf16 = 23.5 MB

typedef __attribute__((ext_vector_type(8))) short s8v;
typedef __attribute__((ext_vector_type(4))) short s4v;
typedef __attribute__((ext_vector_type(4))) float f4v;

__device__ __forceinline__ float b2f(bf16 x){ return __bfloat162float(x); }
__device__ __forceinline__ unsigned short f2bu(float x){
    union { __hip_bfloat16 h; unsigned short u; } cv; cv.h = __float2bfloat16(x); return cv.u;
}
__device__ __forceinline__ float bu2f(unsigned short u){
    union { unsigned int x; float f; } cv; cv.x = ((unsigned int)u) << 16; return cv.f;
}
__device__ __forceinline__ void b2x2(unsigned int u, float& a, float& b){
    union { unsigned int x; float f; } c1, c2;
    c1.x = u << 16; c2.x = u & 0xffff0000u; a = c1.f; b = c2.f;
}
__device__ __forceinline__ unsigned int pk2(float a, float b){
    return (unsigned int)f2bu(a) | ((unsigned int)f2bu(b) << 16);
}
__device__ __forceinline__ int imin(int a,int b){ return a<b?a:b; }
__device__ __forceinline__ int imax(int a,int b){ return a>b?a:b; }

// ---------------------------------------------------------------------------
// dtype probe: bf16 vs fp32 input buffers
// ---------------------------------------------------------------------------
__global__ __launch_bounds__(256) void k_detect(const unsigned int* __restrict__ embw,
                                                float* __restrict__ ws)
{
    __shared__ int cnt;
    if (threadIdx.x == 0) cnt = 0;
    __syncthreads();
    int c = 0;
    for (int i = threadIdx.x; i < 512; i += 256){
        unsigned int e = (embw[i] >> 7) & 0xffu;
        if (e >= 120u && e <= 130u) c++;
    }
    atomicAdd(&cnt, c);
    __syncthreads();
    if (threadIdx.x == 0) ws[OF_FLAG] = (cnt > 256) ? 1.f : 0.f;
}

// ---------------------------------------------------------------------------
// convert: mode 0 fp32 copy; mode 1 bf16 transposed weight (3x256x256);
// mode 2 embed -> bf16 mirror only
// ---------------------------------------------------------------------------
struct ConvArgs {
    const void* src[13];
    int mode[13];
    int n[13];
    int off[13];
};
__global__ __launch_bounds__(256) void k_convert(ConvArgs a, float* __restrict__ ws,
                                                 bf16* __restrict__ bb)
{
    int gid = blockIdx.x*256 + threadIdx.x;
    const int isbf = (ws[OF_FLAG] != 0.f);
#pragma unroll
    for (int t = 0; t < 13; ++t){
        if (gid < a.n[t]){
            float v = isbf ? b2f(((const bf16*)a.src[t])[gid])
                           : ((const float*)a.src[t])[gid];
            if (a.mode[t] == 0){
                ws[a.off[t] + gid] = v;
            } else if (a.mode[t] == 1){
                const int i = gid >> 16, rem = gid & 65535;
                const int k = rem >> 8, nn = rem & 255;
                bb[a.off[t] + (i << 16) + (nn << 8) + k] = __float2bfloat16(v);
            } else {
                bb[BB_INP + gid] = __float2bfloat16(v);
            }
            return;
        }
        gid -= a.n[t];
    }
}

// ---------------------------------------------------------------------------
// halting probability + ACT state update (one block per frame), bf16 inputs
// ---------------------------------------------------------------------------
__global__ __launch_bounds__(128) void k_halt(const bf16* __restrict__ inpb,
        const float* __restrict__ hW, const float* __restrict__ hB,
        float* __restrict__ ws)
{
    __shared__ float hw[H];
    __shared__ float red[128];
    const int f = blockIdx.x, t = threadIdx.x;
    hw[t] = hW[t]; hw[t+128] = hW[t+128];
    __syncthreads();
    const uint4* row = (const uint4*)(inpb + (size_t)(f*P + t)*H);
    float acc = hB[0];
#pragma unroll
    for (int i = 0; i < 16; ++i){
        const uint4 u = row[i];
        float a0,a1,a2,a3,a4,a5,a6,a7;
        b2x2(u.x,a0,a1); b2x2(u.y,a2,a3); b2x2(u.z,a4,a5); b2x2(u.w,a6,a7);
        const int b = i*16;
        acc = fmaf(a0,hw[b+0],acc); acc = fmaf(a1,hw[b+1],acc);
        acc = fmaf(a2,hw[b+2],acc); acc = fmaf(a3,hw[b+3],acc);
        acc = fmaf(a4,hw[b+4],acc); acc = fmaf(a5,hw[b+5],acc);
        acc = fmaf(a6,hw[b+6],acc); acc = fmaf(a7,hw[b+7],acc);
    }
    red[t] = 1.f/(1.f + __expf(-acc));
    __syncthreads();
    for (int s = 64; s > 0; s >>= 1){ if (t < s) red[t] += red[t+s]; __syncthreads(); }
    if (t == 0){
        float pf = red[0] * (1.f/P);
        float pt = ws[OF_PTN + f], rt = ws[OF_RT + f];
        float run  = (pt < 1.f) ? 1.f : 0.f;
        float cond = (pt + pf*run > 0.99f) ? 1.f : 0.f;
        float nh   = cond*run;
        run = (1.f - cond)*run;
        pt += pf*run;
        rt += nh*(1.f - pt);
        pt += nh*rt;
        ws[OF_PTN + f] = pt; ws[OF_RT + f] = rt;
        ws[OF_W   + f] = pf*run + nh*rt;
    }
}

// ---------------------------------------------------------------------------
// QKV projection, all 3 scales fused (blockIdx.z = scale), no window gather:
// only F*P=2304 source rows are projected per scale (windows share rows).
// ---------------------------------------------------------------------------
__global__ __launch_bounds__(256) void k_qkv_mfma(const bf16* __restrict__ X,
        const bf16* __restrict__ WQT, const bf16* __restrict__ WKT,
        const bf16* __restrict__ WVT, const float* __restrict__ fw,
        bf16* __restrict__ qball, bf16* __restrict__ kball, bf16* __restrict__ vball)
{
    const int tid = threadIdx.x;
    const int wave = tid >> 6, lane = tid & 63;
    const int lq = lane & 15, quad = lane >> 4;
    const int m0 = blockIdx.x * 64;
    const int n0 = blockIdx.y * 64 + wave * 16;
    const int i  = blockIdx.z;
    const int wo = i << 16;

    const bf16* arow[4];
#pragma unroll
    for (int mt = 0; mt < 4; ++mt)
        arow[mt] = X + (size_t)(m0 + mt*16 + lq)*H + quad*8;
    const bf16* bqp = WQT + wo + (size_t)(n0 + lq)*H + quad*8;
    const bf16* bkp = WKT + wo + (size_t)(n0 + lq)*H + quad*8;
    const bf16* bvp = WVT + wo + (size_t)(n0 + lq)*H + quad*8;

    f4v aq[4], ak[4], av[4];
#pragma unroll
    for (int mt = 0; mt < 4; ++mt){
        aq[mt] = (f4v){0.f,0.f,0.f,0.f};
        ak[mt] = (f4v){0.f,0.f,0.f,0.f};
        av[mt] = (f4v){0.f,0.f,0.f,0.f};
    }
#pragma unroll
    for (int k0 = 0; k0 < H; k0 += 32){
        const s8v bfq = *(const s8v*)(bqp + k0);
        const s8v bfk = *(const s8v*)(bkp + k0);
        const s8v bfv = *(const s8v*)(bvp + k0);
#pragma unroll
        for (int mt = 0; mt < 4; ++mt){
            const s8v af = *(const s8v*)(arow[mt] + k0);
            aq[mt] = __builtin_amdgcn_mfma_f32_16x16x32_bf16(af, bfq, aq[mt], 0, 0, 0);
            ak[mt] = __builtin_amdgcn_mfma_f32_16x16x32_bf16(af, bfk, ak[mt], 0, 0, 0);
            av[mt] = __builtin_amdgcn_mfma_f32_16x16x32_bf16(af, bfv, av[mt], 0, 0, 0);
        }
    }
    bf16* qo = qball + (size_t)i*RPS;
    bf16* ko = kball + (size_t)i*RPS;
    bf16* vo = vball + (size_t)i*RPS;
    const float bqv = fw[WO2_BQ + i*256 + n0 + lq];
    const float bkv = fw[WO2_BK + i*256 + n0 + lq];
    const float bvv = fw[WO2_BV + i*256 + n0 + lq];
#pragma unroll
    for (int mt = 0; mt < 4; ++mt){
#pragma unroll
        for (int r = 0; r < 4; ++r){
            const size_t row = (size_t)(m0 + mt*16 + quad*4 + r)*H + n0 + lq;
            qo[row] = __float2bfloat16(aq[mt][r] + bqv);
            ko[row] = __float2bfloat16(ak[mt][r] + bkv);
            vo[row] = __float2bfloat16(av[mt][r] + bvv);
        }
    }
}

// ---------------------------------------------------------------------------
// Fused flash attention, all scales in one launch. Per-128k-chunk softmax.
// Epilogue atomicAdds O/(l*cnt) into the per-scale fp32 ao accumulator
// (overlap-add moved BEFORE the linear output projection).
// ---------------------------------------------------------------------------
#if __has_builtin(__builtin_amdgcn_mfma_f32_16x16x16bf16_1k)
#define ATTN_HAVE_1K 1
#else
#define ATTN_HAVE_1K 0
#endif

__global__ __launch_bounds__(256) void k_attn_fused(const bf16* __restrict__ qball,
        const bf16* __restrict__ kball, const bf16* __restrict__ vball,
        float* __restrict__ aoall)
{
    __shared__ unsigned int VT32[32][68];   // V^T chunk: 32 dims x 64 k-pairs
    const int bid = blockIdx.x;
    int i, rel, s, nw, nqt;
    if (bid < 544)       { i = 0; rel = bid;        s = 2; nw = 17; nqt = 4;  }
    else if (bid < 1504) { i = 1; rel = bid - 544;  s = 4; nw = 15; nqt = 8;  }
    else                 { i = 2; rel = bid - 1504; s = 6; nw = 13; nqt = 12; }
    const int nch = nqt >> 1;
    const int qt = rel % nqt;
    const int rest = rel / nqt;
    const int h = rest & 7;
    const int w = rest >> 3;

    const bf16* qs = qball + (size_t)i*RPS;
    const bf16* ks = kball + (size_t)i*RPS;
    const bf16* vs = vball + (size_t)i*RPS;
    float* aos = aoall + (size_t)i*RPS;

    const int tid = threadIdx.x;
    const int wave = tid >> 6, lane = tid & 63;
    const int lq = lane & 15, quad = lane >> 4;
    const int row0 = w*P;
    const int qrow = row0 + qt*64 + wave*16 + lq;

    // Q B-frag, pre-scaled by 1/sqrt(32)
    s8v qf;
    {
        const float SC = 0.17677669529663687f;
        const bf16* qptr = qs + (size_t)qrow*H + h*HD + quad*8;
        union { s8v v; unsigned short u[8]; } qin, qsc;
        qin.v = *(const s8v*)qptr;
#pragma unroll
        for (int j = 0; j < 8; ++j) qsc.u[j] = f2bu(bu2f(qin.u[j]) * SC);
        qf = qsc.v;
    }

    float m = -3e38f, l = 0.f;
    f4v o0 = {0.f,0.f,0.f,0.f}, o1 = {0.f,0.f,0.f,0.f};

    const int kr = tid & 127;
    const int dp = (tid >> 7) << 4;
    const int kp = kr >> 1;
    const bool ev = (tid & 1) == 0;
    const int dbase = ev ? dp : dp + 8;

    for (int ch = 0; ch < nch; ++ch){
        __syncthreads();
        {   // stage V^T via pair-exchange, ds_write_b32, 2-way banks (free)
            const bf16* vsrc = vs + (size_t)(row0 + ch*128 + kr)*H + h*HD + dp;
            const uint4 a = *(const uint4*)vsrc;        // dims dp..dp+7
            const uint4 b = *(const uint4*)(vsrc + 8);  // dims dp+8..dp+15
            unsigned int su[4], ru[4], xu[4], yu[4];
            su[0] = ev ? b.x : a.x; su[1] = ev ? b.y : a.y;
            su[2] = ev ? b.z : a.z; su[3] = ev ? b.w : a.w;
#pragma unroll
            for (int u = 0; u < 4; ++u) ru[u] = (unsigned int)__shfl_xor((int)su[u], 1);
            xu[0] = ev ? a.x : ru[0]; yu[0] = ev ? ru[0] : b.x;
            xu[1] = ev ? a.y : ru[1]; yu[1] = ev ? ru[1] : b.y;
            xu[2] = ev ? a.z : ru[2]; yu[2] = ev ? ru[2] : b.z;
            xu[3] = ev ? a.w : ru[3]; yu[3] = ev ? ru[3] : b.w;
#pragma unroll
            for (int u = 0; u < 4; ++u){
                VT32[dbase + 2*u    ][kp] = (xu[u] & 0xffffu) | (yu[u] << 16);
                VT32[dbase + 2*u + 1][kp] = (xu[u] >> 16) | (yu[u] & 0xffff0000u);
            }
        }
        __syncthreads();

        // 8 independent QK^T MFMAs -> 32 scores/lane (S^T layout: q = lq)
        f4v st[8];
#pragma unroll
        for (int tt = 0; tt < 4; ++tt){
            const bf16* kp0 = ks + (size_t)(row0 + ch*128 + tt*32 + lq)*H + h*HD + quad*8;
            const s8v kf0 = *(const s8v*)kp0;
            const s8v kf1 = *(const s8v*)(kp0 + 16*H);
            f4v z = {0.f,0.f,0.f,0.f};
            st[2*tt]   = __builtin_amdgcn_mfma_f32_16x16x32_bf16(kf0, qf, z, 0, 0, 0);
            st[2*tt+1] = __builtin_amdgcn_mfma_f32_16x16x32_bf16(kf1, qf, z, 0, 0, 0);
        }
        // one softmax update per 128-k chunk
        float mc = -3e38f;
#pragma unroll
        for (int t8 = 0; t8 < 8; ++t8){
            mc = fmaxf(mc, fmaxf(fmaxf(st[t8][0], st[t8][1]), fmaxf(st[t8][2], st[t8][3])));
        }
        mc = fmaxf(mc, __shfl_xor(mc, 16));
        mc = fmaxf(mc, __shfl_xor(mc, 32));
        const float mn = fmaxf(m, mc);
        const float alpha = __expf(m - mn);
        float ls = 0.f;
#pragma unroll
        for (int t8 = 0; t8 < 8; ++t8){
#pragma unroll
            for (int r = 0; r < 4; ++r){
                const float e = __expf(st[t8][r] - mn);
                st[t8][r] = e;
                ls += e;
            }
        }
        ls += __shfl_xor(ls, 16);
        ls += __shfl_xor(ls, 32);
        l = l*alpha + ls;
        m = mn;
        o0 = o0 * alpha;
        o1 = o1 * alpha;

        // PV: P frags direct from C-layout (== B layout of K=16 mfma)
#pragma unroll
        for (int tt = 0; tt < 4; ++tt){
            const int t32 = tt*32;
            const unsigned short* vtb = (const unsigned short*)&VT32[0][0];
#if ATTN_HAVE_1K
            union { unsigned int u[2]; s4v v; } pf0, pf1;
            pf0.u[0] = pk2(st[2*tt][0],   st[2*tt][1]);
            pf0.u[1] = pk2(st[2*tt][2],   st[2*tt][3]);
            pf1.u[0] = pk2(st[2*tt+1][0], st[2*tt+1][1]);
            pf1.u[1] = pk2(st[2*tt+1][2], st[2*tt+1][3]);
            const s4v va00 = *(const s4v*)(vtb + (size_t)lq*136      + t32      + (quad<<2));
            const s4v va01 = *(const s4v*)(vtb + (size_t)lq*136      + t32 + 16 + (quad<<2));
            const s4v va10 = *(const s4v*)(vtb + (size_t)(lq+16)*136 + t32      + (quad<<2));
            const s4v va11 = *(const s4v*)(vtb + (size_t)(lq+16)*136 + t32 + 16 + (quad<<2));
            o0 = __builtin_amdgcn_mfma_f32_16x16x16bf16_1k(va00, pf0.v, o0, 0, 0, 0);
            o0 = __builtin_amdgcn_mfma_f32_16x16x16bf16_1k(va01, pf1.v, o0, 0, 0, 0);
            o1 = __builtin_amdgcn_mfma_f32_16x16x16bf16_1k(va10, pf0.v, o1, 0, 0, 0);
            o1 = __builtin_amdgcn_mfma_f32_16x16x16bf16_1k(va11, pf1.v, o1, 0, 0, 0);
#else
            const unsigned int p0x = pk2(st[2*tt][0],   st[2*tt][1]);
            const unsigned int p0y = pk2(st[2*tt][2],   st[2*tt][3]);
            const unsigned int p1x = pk2(st[2*tt+1][0], st[2*tt+1][1]);
            const unsigned int p1y = pk2(st[2*tt+1][2], st[2*tt+1][3]);
            const int srcA = lq + ((( quad<<1)      & 3) << 4);
            const int srcB = lq + ((((quad<<1) | 1) & 3) << 4);
            const unsigned int a0 = (unsigned int)__shfl((int)p0x, srcA);
            const unsigned int a1 = (unsigned int)__shfl((int)p0y, srcA);
            const unsigned int a2 = (unsigned int)__shfl((int)p0x, srcB);
            const unsigned int a3 = (unsigned int)__shfl((int)p0y, srcB);
            const unsigned int b0 = (unsigned int)__shfl((int)p1x, srcA);
            const unsigned int b1 = (unsigned int)__shfl((int)p1y, srcA);
            const unsigned int b2 = (unsigned int)__shfl((int)p1x, srcB);
            const unsigned int b3 = (unsigned int)__shfl((int)p1y, srcB);
            const bool hi = (quad >= 2);
            union { unsigned int u[4]; s8v v; } bfr;
            bfr.u[0] = hi ? b0 : a0; bfr.u[1] = hi ? b1 : a1;
            bfr.u[2] = hi ? b2 : a2; bfr.u[3] = hi ? b3 : a3;
            const s8v va0 = *(const s8v*)(vtb + (size_t)lq*136      + t32 + (quad<<3));
            const s8v va1 = *(const s8v*)(vtb + (size_t)(lq+16)*136 + t32 + (quad<<3));
            o0 = __builtin_amdgcn_mfma_f32_16x16x32_bf16(va0, bfr.v, o0, 0, 0, 0);
            o1 = __builtin_amdgcn_mfma_f32_16x16x32_bf16(va1, bfr.v, o1, 0, 0, 0);
#endif
        }
    }
    // epilogue: lane holds O^T[d=quad*4+r (+16)][q=lq]; overlap-add into ao
    const int fframe = qrow >> 7;
    const int cnt = imin(nw-1, fframe) - imax(0, fframe - s + 1) + 1;
    const float scl = 1.f / (l * (float)cnt);
    float* dst = aos + (size_t)qrow*H + h*HD;
#pragma unroll
    for (int r = 0; r < 4; ++r){
        atomicAdd(dst + (quad<<2) + r,      o0[r]*scl);
        atomicAdd(dst + 16 + (quad<<2) + r, o1[r]*scl);
    }
}

// ---------------------------------------------------------------------------
// Output projection over the frame grid (2304 rows), all 3 scales accumulated
// in one MFMA accumulator, fused with the transition epilogue.
// ---------------------------------------------------------------------------
__global__ __launch_bounds__(256) void k_oproj_trans(const float* __restrict__ aoall,
        const bf16* __restrict__ WOT, const float* __restrict__ ws,
        bf16* __restrict__ inpb, float* __restrict__ context)
{
    const int tid = threadIdx.x;
    const int wave = tid >> 6, lane = tid & 63;
    const int lq = lane & 15, quad = lane >> 4;
    const int m0 = blockIdx.x * 64;
    const int n0 = blockIdx.y * 64 + wave * 16;

    f4v acc[4];
#pragma unroll
    for (int mt = 0; mt < 4; ++mt) acc[mt] = (f4v){0.f,0.f,0.f,0.f};

    for (int i = 0; i < 3; ++i){
        const float* A = aoall + (size_t)i*RPS;
        const bf16* bp = WOT + (i<<16) + (size_t)(n0 + lq)*H + quad*8;
#pragma unroll
        for (int k0 = 0; k0 < H; k0 += 32){
            const s8v bf_ = *(const s8v*)(bp + k0);
#pragma unroll
            for (int mt = 0; mt < 4; ++mt){
                const float* ap = A + (size_t)(m0 + mt*16 + lq)*H + k0 + quad*8;
                const float4 a0 = *(const float4*)ap;
                const float4 a1 = *(const float4*)(ap + 4);
                union { unsigned int u[4]; s8v v; } af;
                af.u[0] = pk2(a0.x, a0.y); af.u[1] = pk2(a0.z, a0.w);
                af.u[2] = pk2(a1.x, a1.y); af.u[3] = pk2(a1.z, a1.w);
                acc[mt] = __builtin_amdgcn_mfma_f32_16x16x32_bf16(af.v, bf_, acc[mt], 0, 0, 0);
            }
        }
    }
    const int col = n0 + lq;
    const float bosum = ws[OF_FW + WO2_BO + col] + ws[OF_FW + WO2_BO + 256 + col]
                      + ws[OF_FW + WO2_BO + 512 + col];
#pragma unroll
    for (int mt = 0; mt < 4; ++mt){
#pragma unroll
        for (int r = 0; r < 4; ++r){
            const int row = m0 + mt*16 + quad*4 + r;
            const float tval = 0.25f * (acc[mt][r] + bosum);
            const float wf = ws[OF_W + (row >> 7)];
            const size_t idx = (size_t)row*H + col;
            inpb[idx] = __float2bfloat16(tval);
            context[idx] = tval*wf + context[idx]*(1.f - wf);
        }
    }
}

// ---------------------------------------------------------------------------
// reduce context over all rows -> osum[256]
// ---------------------------------------------------------------------------
__global__ __launch_bounds__(256) void k_reduce(const float* __restrict__ context,
        float* __restrict__ osum)
{
    const int hcol = threadIdx.x;
    const float* base = context + (size_t)blockIdx.x * 64 * H;
    float s = 0.f;
#pragma unroll 8
    for (int r = 0; r < 64; ++r) s += base[(size_t)r*H + hcol];
    atomicAdd(&osum[hcol], s);
}

// ---------------------------------------------------------------------------
// classes = osum @ cls_W + cls_b
// ---------------------------------------------------------------------------
__global__ __launch_bounds__(256) void k_classes(const float* __restrict__ ws,
        void* __restrict__ out)
{
    __shared__ float os[H];
    const int tid = threadIdx.x;
    os[tid] = ws[OF_OSUM + tid];
    __syncthreads();
    const int n = blockIdx.x*256 + tid;
    if (n < NCLS){
        const float* clsW = ws + OF_FW + WO2_CLSW;
        float acc = ws[OF_FW + WO2_CLSB + n];
        for (int hh = 0; hh < H; ++hh) acc = fmaf(os[hh], clsW[(size_t)hh*NCLS + n], acc);
        if (ws[OF_FLAG] != 0.f) ((bf16*)out)[n] = __float2bfloat16(acc);
        else                    ((float*)out)[n] = acc;
    }
}

// ---------------------------------------------------------------------------
extern "C" void kernel_launch(void* const* d_in, const int* in_sizes, int n_in,
                              void* d_out, int out_size, void* d_ws, size_t ws_size,
                              hipStream_t stream)
{
    (void)in_sizes; (void)n_in; (void)out_size; (void)ws_size;
    float* WS = (float*)d_ws;
    float* context = WS + OF_CTX;
    float* ao      = WS + OF_AO;
    float* fw      = WS + OF_FW;
    bf16*  bb      = (bf16*)(WS + NF_TOTAL);
    bf16*  inpb    = bb + BB_INP;
    bf16*  qb      = bb + BB_QB;
    bf16*  kb      = bb + BB_KB;
    bf16*  vb      = bb + BB_VB;

    (void)hipMemsetAsync(WS, 0, (size_t)OF_AO*4, stream);   // state + context
    k_detect<<<1, 256, 0, stream>>>((const unsigned int*)d_in[0], WS);

    ConvArgs ca;
    const int srcs[13]  = {0, 3, 4, 8, 9, 11, 13, 15, 17, 10, 12, 14, 16};
    const int modes[13] = {2, 0, 0, 0, 0, 0, 0, 0, 0, 1, 1, 1, 1};
    const int ns[13]    = {FPH, 256, 1, H*NCLS, NCLS, 768, 768, 768, 768,
                           196608, 196608, 196608, 196608};
    const int offs[13]  = {0,
        OF_FW+WO2_HALTW, OF_FW+WO2_HALTB, OF_FW+WO2_CLSW, OF_FW+WO2_CLSB,
        OF_FW+WO2_BQ, OF_FW+WO2_BK, OF_FW+WO2_BV, OF_FW+WO2_BO,
        BB_WQT, BB_WKT, BB_WVT, BB_WOT};
    int total = 0;
    for (int t = 0; t < 13; ++t){
        ca.src[t] = d_in[srcs[t]]; ca.mode[t] = modes[t];
        ca.n[t] = ns[t]; ca.off[t] = offs[t]; total += ns[t];
    }
    k_convert<<<(total + 255)/256, 256, 0, stream>>>(ca, WS, bb);

    for (int it = 0; it < 2; ++it){
        k_halt<<<F, 128, 0, stream>>>(inpb, fw + WO2_HALTW, fw + WO2_HALTB, WS);
        (void)hipMemsetAsync(ao, 0, (size_t)(3*RPS)*4, stream);
        k_qkv_mfma<<<dim3(36, 4, 3), 256, 0, stream>>>(inpb,
            bb+BB_WQT, bb+BB_WKT, bb+BB_WVT, fw, qb, kb, vb);
        k_attn_fused<<<2752, 256, 0, stream>>>(qb, kb, vb, ao);
        k_oproj_trans<<<dim3(36, 4), 256, 0, stream>>>(ao, bb+BB_WOT, WS,
            inpb, context);
    }
    k_reduce<<<36, 256, 0, stream>>>(context, WS + OF_OSUM);
    k_classes<<<3, 256, 0, stream>>>(WS, d_out);
}